// Round 3
// baseline (587.312 us; speedup 1.0000x reference)
//
#include <hip/hip_runtime.h>

typedef __attribute__((ext_vector_type(8))) __bf16 bf16x8;
typedef __attribute__((ext_vector_type(4))) float f32x4;

__device__ __forceinline__ ushort f2bf(float f) {
  union { float f; unsigned u; } x; x.f = f;
  unsigned r = x.u + 0x7FFFu + ((x.u >> 16) & 1u);
  return (ushort)(r >> 16);
}
__device__ __forceinline__ float bf2f(ushort u) {
  union { unsigned u; float f; } x; x.u = ((unsigned)u) << 16;
  return x.f;
}

__device__ __forceinline__ void gload_lds16(const void* g, void* l) {
  __builtin_amdgcn_global_load_lds(
      (const __attribute__((address_space(1))) void*)g,
      (__attribute__((address_space(3))) void*)l, 16, 0, 0);
}

// ---------------- fp32 -> bf16 convert ----------------
__global__ __launch_bounds__(256) void cvt_f32_bf16(const float4* __restrict__ in,
                                                    ushort4* __restrict__ out, int n4) {
  int i = blockIdx.x * 256 + threadIdx.x;
  if (i >= n4) return;
  float4 v = in[i];
  ushort4 o;
  o.x = f2bf(v.x); o.y = f2bf(v.y); o.z = f2bf(v.z); o.w = f2bf(v.w);
  out[i] = o;
}

// ---------------- generic B^T-form bf16 MFMA GEMM ----------------
// C[m,n] = (sum_k A[m,k]*B[n,k]) * (SCALED?scale:1) + bias
// 1D grid = gm*gn*batches with XCD-chunk swizzle + banded tile order:
//  - bijective XCD swizzle (m204): wid = (wg%8)*(nwg/8) + wg/8   [nwg%8==0]
//  - within chunk: bands of 4 N-tiles, M advances inside band -> one XCD's
//    consecutive blocks reuse 4 B-panels from L2 while streaming A-panels once.
// BIAS_MODE: 0 none, 1 bias[n], 2 bias[m].  OUT_BF16: 1 bf16, 0 fp32.
template<int OUT_BF16, int BIAS_MODE, int SCALED>
__global__ __launch_bounds__(256) void gemm_bt(
    const ushort* __restrict__ A, const ushort* __restrict__ B,
    void* __restrict__ Cv, const float* __restrict__ bias,
    int N, int K, long sA, long sB, long sC, float scale, int gm, int gn)
{
  __shared__ ushort At[2][128 * 32];
  __shared__ ushort Bt[2][128 * 32];

  // ---- tile decode with swizzle ----
  const int nwg = gridDim.x;
  const int wg = blockIdx.x;
  const int cpx = nwg >> 3;
  const int wid = (wg & 7) * cpx + (wg >> 3);
  const int tiles = gm * gn;
  const int bz = wid / tiles;
  const int t2 = wid - bz * tiles;
  const int band = t2 / (gm << 2);
  const int r2 = t2 - band * (gm << 2);
  const int tile_m = (r2 >> 2) * 128;
  const int tile_n = ((band << 2) + (r2 & 3)) * 128;

  const ushort* Ab = A + (size_t)bz * sA;
  const ushort* Bb = B + (size_t)bz * sB;
  const int t = threadIdx.x;
  const int lane = t & 63;
  const int m_off = ((t >> 6) >> 1) * 64;
  const int n_off = ((t >> 6) & 1) * 64;

  f32x4 acc[4][4] = {};

#define STAGE(p, k0)                                                                     \
  do {                                                                                   \
    for (int i = 0; i < 2; ++i) {                                                        \
      int o = t * 16 + i * 4096;                                                         \
      int r = o >> 6, cb = o & 63;                                                       \
      gload_lds16((const char*)(Ab + (size_t)(tile_m + r) * K + (k0)) + cb,              \
                  (char*)&At[p][0] + o);                                                 \
      gload_lds16((const char*)(Bb + (size_t)(tile_n + r) * K + (k0)) + cb,              \
                  (char*)&Bt[p][0] + o);                                                 \
    }                                                                                    \
  } while (0)

  STAGE(0, 0);
  const int KT = K >> 5;
  for (int kt = 0; kt < KT; ++kt) {
    const int p = kt & 1;
    __syncthreads();
    if (kt + 1 < KT) STAGE(p ^ 1, (kt + 1) * 32);
    bf16x8 af[4], bfr[4];
#pragma unroll
    for (int x = 0; x < 4; ++x) {
      af[x]  = *(const bf16x8*)&At[p][(m_off + x * 16 + (lane & 15)) * 32 + (lane >> 4) * 8];
      bfr[x] = *(const bf16x8*)&Bt[p][(n_off + x * 16 + (lane & 15)) * 32 + (lane >> 4) * 8];
    }
#pragma unroll
    for (int mi = 0; mi < 4; ++mi)
#pragma unroll
      for (int ni = 0; ni < 4; ++ni)
        acc[mi][ni] = __builtin_amdgcn_mfma_f32_16x16x32_bf16(af[mi], bfr[ni], acc[mi][ni], 0, 0, 0);
  }
#undef STAGE

  const int r0 = tile_m + m_off + ((lane >> 4) * 4);
  const int c0 = tile_n + n_off + (lane & 15);
#pragma unroll
  for (int ni = 0; ni < 4; ++ni) {
    const int cc = c0 + ni * 16;
    float bc = 0.f;
    if (BIAS_MODE == 1) bc = bias[cc];
#pragma unroll
    for (int mi = 0; mi < 4; ++mi) {
#pragma unroll
      for (int j = 0; j < 4; ++j) {
        int rr = r0 + mi * 16 + j;
        float val = acc[mi][ni][j];
        if (SCALED) val *= scale;
        if (BIAS_MODE == 1) val += bc;
        else if (BIAS_MODE == 2) val += bias[rr];
        size_t idx = (size_t)bz * sC + (size_t)rr * N + cc;
        if (OUT_BF16) ((ushort*)Cv)[idx] = f2bf(val);
        else          ((float*)Cv)[idx] = val;
      }
    }
  }
}

// ============ chunked column softmax (softmax over ROW axis per column) ============
template<int BF16IN>
__global__ __launch_bounds__(256) void colsm_pass1(
    const void* __restrict__ X, float* __restrict__ red_max, float* __restrict__ red_sum,
    int rows, int cols, int rpc)
{
  const int b = blockIdx.y;
  const int nch = gridDim.z;
  const int ch = blockIdx.z;
  const size_t base = (size_t)b * rows * cols;
  const int c4 = (blockIdx.x * 256 + threadIdx.x) * 4;
  const int r0 = ch * rpc;
  float mx[4] = {-1e30f, -1e30f, -1e30f, -1e30f};
  float sm[4] = {0.f, 0.f, 0.f, 0.f};
  for (int r = r0; r < r0 + rpc; ++r) {
    float v[4];
    if (BF16IN) {
      ushort4 u = *(const ushort4*)((const ushort*)X + base + (size_t)r * cols + c4);
      v[0] = bf2f(u.x); v[1] = bf2f(u.y); v[2] = bf2f(u.z); v[3] = bf2f(u.w);
    } else {
      float4 u = *(const float4*)((const float*)X + base + (size_t)r * cols + c4);
      v[0] = u.x; v[1] = u.y; v[2] = u.z; v[3] = u.w;
    }
#pragma unroll
    for (int i = 0; i < 4; ++i) {
      float nm = fmaxf(mx[i], v[i]);
      sm[i] = sm[i] * __expf(mx[i] - nm) + __expf(v[i] - nm);
      mx[i] = nm;
    }
  }
  size_t ro = ((size_t)b * nch + ch) * cols + c4;
#pragma unroll
  for (int i = 0; i < 4; ++i) { red_max[ro + i] = mx[i]; red_sum[ro + i] = sm[i]; }
}

__global__ __launch_bounds__(256) void colsm_combine(
    const float* __restrict__ red_max, const float* __restrict__ red_sum,
    float* __restrict__ Mv, float* __restrict__ Zinv, int cols, int nch)
{
  const int b = blockIdx.y;
  const int c = blockIdx.x * 256 + threadIdx.x;
  float M = -1e30f, Z = 0.f;
  for (int ch = 0; ch < nch; ++ch) {
    size_t o = ((size_t)b * nch + ch) * cols + c;
    float m = red_max[o], s = red_sum[o];
    float nm = fmaxf(M, m);
    Z = Z * __expf(M - nm) + s * __expf(m - nm);
    M = nm;
  }
  Mv[(size_t)b * cols + c] = M;
  Zinv[(size_t)b * cols + c] = 1.f / Z;
}

__global__ __launch_bounds__(256) void colsm_emit_bf16(
    const ushort* __restrict__ X, ushort* __restrict__ P,
    const float* __restrict__ Mv, const float* __restrict__ Zinv,
    int rows, int cols, int rpc)
{
  const int b = blockIdx.y;
  const int ch = blockIdx.z;
  const size_t base = (size_t)b * rows * cols;
  const int c4 = (blockIdx.x * 256 + threadIdx.x) * 4;
  const int r0 = ch * rpc;
  float M[4], Zi[4];
#pragma unroll
  for (int i = 0; i < 4; ++i) {
    M[i] = Mv[(size_t)b * cols + c4 + i];
    Zi[i] = Zinv[(size_t)b * cols + c4 + i];
  }
  for (int r = r0; r < r0 + rpc; ++r) {
    size_t o = base + (size_t)r * cols + c4;
    ushort4 u = *(const ushort4*)(X + o);
    ushort4 w;
    w.x = f2bf(__expf(bf2f(u.x) - M[0]) * Zi[0]);
    w.y = f2bf(__expf(bf2f(u.y) - M[1]) * Zi[1]);
    w.z = f2bf(__expf(bf2f(u.z) - M[2]) * Zi[2]);
    w.w = f2bf(__expf(bf2f(u.w) - M[3]) * Zi[3]);
    *(ushort4*)(P + o) = w;
  }
}

__global__ __launch_bounds__(256) void final_emit(
    const float* __restrict__ attn, const float* __restrict__ q,
    float* __restrict__ out0, float* __restrict__ out1,
    const float* __restrict__ Mv, const float* __restrict__ Zinv,
    int rows, int cols, int rpc)
{
  const int b = blockIdx.y;
  const int ch = blockIdx.z;
  const size_t base = (size_t)b * rows * cols;
  const int c4 = (blockIdx.x * 256 + threadIdx.x) * 4;
  const int r0 = ch * rpc;
  float M[4], Zi[4];
#pragma unroll
  for (int i = 0; i < 4; ++i) {
    M[i] = Mv[(size_t)b * cols + c4 + i];
    Zi[i] = Zinv[(size_t)b * cols + c4 + i];
  }
  for (int r = r0; r < r0 + rpc; ++r) {
    size_t o = base + (size_t)r * cols + c4;
    float4 a = *(const float4*)(attn + o);
    float4 qv = *(const float4*)(q + o);
    float4 w, s;
    w.x = __expf(a.x - M[0]) * Zi[0];
    w.y = __expf(a.y - M[1]) * Zi[1];
    w.z = __expf(a.z - M[2]) * Zi[2];
    w.w = __expf(a.w - M[3]) * Zi[3];
    s.x = a.x + qv.x; s.y = a.y + qv.y; s.z = a.z + qv.z; s.w = a.w + qv.w;
    *(float4*)(out1 + o) = w;
    *(float4*)(out0 + o) = s;
  }
}

extern "C" void kernel_launch(void* const* d_in, const int* in_sizes, int n_in,
                              void* d_out, int out_size, void* d_ws, size_t ws_size,
                              hipStream_t stream) {
  const float* q  = (const float*)d_in[0];
  const float* k  = (const float*)d_in[1];
  const float* v  = (const float*)d_in[2];
  const float* Wq = (const float*)d_in[3];
  const float* bq = (const float*)d_in[4];
  const float* Wk = (const float*)d_in[5];
  const float* bk = (const float*)d_in[6];
  const float* Wv = (const float*)d_in[7];
  const float* bv = (const float*)d_in[8];
  float* out = (float*)d_out;

  const int B = 8, S = 2048, D = 1024;
  const long BS = (long)B * S;
  const long nQKV = BS * D;
  const long nW = (long)D * D;

  ushort* qb  = (ushort*)d_out;
  ushort* kb  = qb + nQKV;
  ushort* vb  = kb + nQKV;
  ushort* Wqb = vb + nQKV;
  ushort* Wkb = Wqb + nW;
  ushort* Wvb = Wkb + nW;

  char* ws = (char*)d_ws;
  ushort* qp     = (ushort*)ws;
  ushort* kp     = (ushort*)(ws + (32ull << 20));
  ushort* vpT    = (ushort*)(ws + (64ull << 20));
  ushort* scores = (ushort*)(ws + (96ull << 20));
  ushort* probs  = (ushort*)ws;
  float*  attn   = (float*)(ws + (96ull << 20));

  const int RPC = 16;
  const int NCH = S / RPC;

  float* red_s_max = (float*)d_out;
  float* red_s_sum = red_s_max + (size_t)B * NCH * S;
  float* Ms        = red_s_sum + (size_t)B * NCH * S;
  float* Zs        = Ms + (size_t)B * S;

  float* red_f_max = (float*)ws;
  float* red_f_sum = red_f_max + (size_t)B * NCH * D;
  float* Mf        = red_f_sum + (size_t)B * NCH * D;
  float* Zf        = Mf + (size_t)B * D;

  auto cvt = [&](const float* src, ushort* dst, long n) {
    int n4 = (int)(n / 4);
    cvt_f32_bf16<<<dim3((n4 + 255) / 256), 256, 0, stream>>>((const float4*)src, (ushort4*)dst, n4);
  };
  cvt(q, qb, nQKV);
  cvt(k, kb, nQKV);
  cvt(v, vb, nQKV);
  cvt(Wq, Wqb, nW);
  cvt(Wk, Wkb, nW);
  cvt(Wv, Wvb, nW);

  // qp[m][e] = q[m][:]·Wq[e][:] + bq[e]   gm=128, gn=8
  gemm_bt<1, 1, 0><<<dim3(128 * 8), 256, 0, stream>>>(
      qb, Wqb, qp, bq, D, D, 0, 0, 0, 1.f, 128, 8);
  // kp
  gemm_bt<1, 1, 0><<<dim3(128 * 8), 256, 0, stream>>>(
      kb, Wkb, kp, bk, D, D, 0, 0, 0, 1.f, 128, 8);
  // vpT[b][e][s] = Wv[e][:]·v[b][s][:] + bv[e]   gm=8, gn=16, batch 8
  gemm_bt<1, 2, 0><<<dim3(8 * 16 * B), 256, 0, stream>>>(
      Wvb, vb, vpT, bv, S, D, 0, (long)S * D, (long)D * S, 1.f, 8, 16);
  // scores[b][q][k] = qp·kp / 1024   gm=16, gn=16, batch 8
  gemm_bt<1, 0, 1><<<dim3(16 * 16 * B), 256, 0, stream>>>(
      qp, kp, scores, nullptr, S, D, (long)S * D, (long)S * D, (long)S * S, 1.f / 1024.f, 16, 16);

  colsm_pass1<1><<<dim3(S / 1024, B, NCH), 256, 0, stream>>>(
      scores, red_s_max, red_s_sum, S, S, RPC);
  colsm_combine<<<dim3(S / 256, B), 256, 0, stream>>>(red_s_max, red_s_sum, Ms, Zs, S, NCH);
  colsm_emit_bf16<<<dim3(S / 1024, B, NCH), 256, 0, stream>>>(
      scores, probs, Ms, Zs, S, S, RPC);

  // attn[b][q][d] = probs·vpT   gm=16, gn=8, batch 8
  gemm_bt<0, 0, 0><<<dim3(16 * 8 * B), 256, 0, stream>>>(
      probs, vpT, attn, nullptr, D, S, (long)S * S, (long)D * S, (long)S * D, 1.f, 16, 8);

  colsm_pass1<0><<<dim3(D / 1024, B, NCH), 256, 0, stream>>>(
      attn, red_f_max, red_f_sum, S, D, RPC);
  colsm_combine<<<dim3(D / 256, B), 256, 0, stream>>>(red_f_max, red_f_sum, Mf, Zf, D, NCH);
  final_emit<<<dim3(D / 1024, B, NCH), 256, 0, stream>>>(
      attn, q, out, out + nQKV, Mf, Zf, S, D, RPC);

  (void)in_sizes; (void)n_in; (void)out_size; (void)ws_size;
}

// Round 4
// 557.568 us; speedup vs baseline: 1.0533x; 1.0533x over previous
//
#include <hip/hip_runtime.h>

typedef __attribute__((ext_vector_type(8))) __bf16 bf16x8;
typedef __attribute__((ext_vector_type(8))) ushort u16x8;
typedef __attribute__((ext_vector_type(4))) float f32x4;

__device__ __forceinline__ ushort f2bf(float f) {
  union { float f; unsigned u; } x; x.f = f;
  unsigned r = x.u + 0x7FFFu + ((x.u >> 16) & 1u);
  return (ushort)(r >> 16);
}
__device__ __forceinline__ float bf2f(ushort u) {
  union { unsigned u; float f; } x; x.u = ((unsigned)u) << 16;
  return x.f;
}

__device__ __forceinline__ void gload_lds16(const void* g, void* l) {
  __builtin_amdgcn_global_load_lds(
      (const __attribute__((address_space(1))) void*)g,
      (__attribute__((address_space(3))) void*)l, 16, 0, 0);
}

// ---------------- fp32 -> bf16 convert (weights only) ----------------
__global__ __launch_bounds__(256) void cvt_f32_bf16(const float4* __restrict__ in,
                                                    ushort4* __restrict__ out, int n4) {
  int i = blockIdx.x * 256 + threadIdx.x;
  if (i >= n4) return;
  float4 v = in[i];
  ushort4 o;
  o.x = f2bf(v.x); o.y = f2bf(v.y); o.z = f2bf(v.z); o.w = f2bf(v.w);
  out[i] = o;
}

// ---------------- generic B^T-form bf16 MFMA GEMM ----------------
// C[m,n] = (sum_k A[m,k]*B[n,k]) * (SCALED?scale:1) + bias
// A_F32/B_F32: that operand is fp32 in global; converted to bf16 during the
// reg-staged LDS write (saves the separate cvt kernel + round trip).
// REDUCE: epilogue additionally emits per-tile column (max, sumexp) partials
// (softmax pass1 fused): red_*[bz*gm + tile_m/128][N] rows.
// BIAS_MODE: 0 none, 1 bias[n], 2 bias[m].  OUT_BF16: 1 bf16, 0 fp32.
template<int OUT_BF16, int BIAS_MODE, int SCALED, int A_F32, int B_F32, int REDUCE>
__global__ __launch_bounds__(256) void gemm_bt(
    const void* __restrict__ Av, const void* __restrict__ Bv,
    void* __restrict__ Cv, const float* __restrict__ bias,
    float* __restrict__ red_max, float* __restrict__ red_sum,
    int N, int K, long sA, long sB, long sC, float scale, int gm, int gn)
{
  __shared__ ushort At[2][128 * 32];
  __shared__ ushort Bt[2][128 * 32];

  // ---- tile decode: bijective XCD swizzle + banded order ----
  const int nwg = gridDim.x;
  const int wg = blockIdx.x;
  const int cpx = nwg >> 3;
  const int wid = (wg & 7) * cpx + (wg >> 3);
  const int tiles = gm * gn;
  const int bz = wid / tiles;
  const int t2 = wid - bz * tiles;
  const int band = t2 / (gm << 2);
  const int r2 = t2 - band * (gm << 2);
  const int tile_m = (r2 >> 2) * 128;
  const int tile_n = ((band << 2) + (r2 & 3)) * 128;

  const ushort* Ab = A_F32 ? nullptr : (const ushort*)Av + (size_t)bz * sA;
  const float*  AbF = A_F32 ? (const float*)Av + (size_t)bz * sA : nullptr;
  const ushort* Bb = B_F32 ? nullptr : (const ushort*)Bv + (size_t)bz * sB;
  const float*  BbF = B_F32 ? (const float*)Bv + (size_t)bz * sB : nullptr;

  const int t = threadIdx.x;
  const int lane = t & 63;
  const int m_off = ((t >> 6) >> 1) * 64;
  const int n_off = ((t >> 6) & 1) * 64;
  const int srow = t >> 1;              // reg-stage: row in tile
  const int skq = (t & 1) * 16;         // reg-stage: k-offset (elements)

  f32x4 acc[4][4] = {};

  // gload staging of one 128x32 bf16 tile (8KB)
#define STAGE_G(dstbuf, src, tile, k0)                                                  \
  do {                                                                                  \
    for (int i = 0; i < 2; ++i) {                                                       \
      int o = t * 16 + i * 4096;                                                        \
      int r = o >> 6, cb = o & 63;                                                      \
      gload_lds16((const char*)((src) + (size_t)((tile) + r) * K + (k0)) + cb,          \
                  (char*)&(dstbuf)[0] + o);                                             \
    }                                                                                   \
  } while (0)

  // reg staging: load 16 fp32, convert, 2x ds_write_b128
#define RLOAD(Lx, srcF, tile, k0)                                                       \
  do {                                                                                  \
    const float4* s =                                                                   \
        (const float4*)((srcF) + (size_t)((tile) + srow) * K + (k0) + skq);             \
    Lx[0] = s[0]; Lx[1] = s[1]; Lx[2] = s[2]; Lx[3] = s[3];                             \
  } while (0)
#define RWRITE(Lx, dstbuf)                                                              \
  do {                                                                                  \
    u16x8 w0, w1;                                                                       \
    const float* f = (const float*)&Lx[0];                                              \
    for (int j = 0; j < 8; ++j) w0[j] = f2bf(f[j]);                                     \
    for (int j = 0; j < 8; ++j) w1[j] = f2bf(f[8 + j]);                                 \
    *(__attribute__((address_space(3))) u16x8*)&(dstbuf)[t * 16] = w0;                  \
    *(__attribute__((address_space(3))) u16x8*)&(dstbuf)[t * 16 + 8] = w1;              \
  } while (0)

  // ---- prologue: stage K-tile 0 into buf 0 ----
  {
    float4 La[4], Lb[4];
    if constexpr (A_F32) { RLOAD(La, AbF, tile_m, 0); RWRITE(La, At[0]); }
    else                 STAGE_G(At[0], Ab, tile_m, 0);
    if constexpr (B_F32) { RLOAD(Lb, BbF, tile_n, 0); RWRITE(Lb, Bt[0]); }
    else                 STAGE_G(Bt[0], Bb, tile_n, 0);
  }

  const int KT = K >> 5;
  for (int kt = 0; kt < KT; ++kt) {
    const int p = kt & 1;
    __syncthreads();   // drains gloads + ds_writes; orders vs all waves' reads
    const bool pf = (kt + 1 < KT);
    const int k0n = (kt + 1) * 32;
    float4 La[4], Lb[4];
    if constexpr (A_F32) { if (pf) RLOAD(La, AbF, tile_m, k0n); }
    else                 { if (pf) STAGE_G(At[p ^ 1], Ab, tile_m, k0n); }
    if constexpr (B_F32) { if (pf) RLOAD(Lb, BbF, tile_n, k0n); }
    else                 { if (pf) STAGE_G(Bt[p ^ 1], Bb, tile_n, k0n); }

    bf16x8 af[4], bfr[4];
#pragma unroll
    for (int x = 0; x < 4; ++x) {
      af[x]  = *(const bf16x8*)&At[p][(m_off + x * 16 + (lane & 15)) * 32 + (lane >> 4) * 8];
      bfr[x] = *(const bf16x8*)&Bt[p][(n_off + x * 16 + (lane & 15)) * 32 + (lane >> 4) * 8];
    }
#pragma unroll
    for (int mi = 0; mi < 4; ++mi)
#pragma unroll
      for (int ni = 0; ni < 4; ++ni)
        acc[mi][ni] = __builtin_amdgcn_mfma_f32_16x16x32_bf16(af[mi], bfr[ni], acc[mi][ni], 0, 0, 0);

    if constexpr (A_F32) { if (pf) RWRITE(La, At[p ^ 1]); }
    if constexpr (B_F32) { if (pf) RWRITE(Lb, Bt[p ^ 1]); }
  }
#undef STAGE_G
#undef RLOAD
#undef RWRITE

  // ---- epilogue ----
  float* rmaxL = (float*)&At[0][0];      // [8][128] alias (REDUCE only)
  float* rsumL = rmaxL + 1024;
  if constexpr (REDUCE) __syncthreads();  // all LDS reads done before alias write

  const int r0 = tile_m + m_off + ((lane >> 4) * 4);
  const int c0 = tile_n + n_off + (lane & 15);
  const int contrib = (m_off >> 6) * 4 + (lane >> 4);   // 0..7
#pragma unroll
  for (int ni = 0; ni < 4; ++ni) {
    const int cc = c0 + ni * 16;
    float bc = 0.f;
    if (BIAS_MODE == 1) bc = bias[cc];
    float vals[16];
    float mx = -1e30f;
#pragma unroll
    for (int mi = 0; mi < 4; ++mi) {
#pragma unroll
      for (int j = 0; j < 4; ++j) {
        int rr = r0 + mi * 16 + j;
        float val = acc[mi][ni][j];
        if (SCALED) val *= scale;
        if (BIAS_MODE == 1) val += bc;
        else if (BIAS_MODE == 2) val += bias[rr];
        if (REDUCE) { vals[mi * 4 + j] = val; mx = fmaxf(mx, val); }
        size_t idx = (size_t)bz * sC + (size_t)rr * N + cc;
        if (OUT_BF16) ((ushort*)Cv)[idx] = f2bf(val);
        else          ((float*)Cv)[idx] = val;
      }
    }
    if constexpr (REDUCE) {
      float sm = 0.f;
#pragma unroll
      for (int x = 0; x < 16; ++x) sm += __expf(vals[x] - mx);
      int colloc = n_off + ni * 16 + (lane & 15);
      rmaxL[contrib * 128 + colloc] = mx;
      rsumL[contrib * 128 + colloc] = sm;
    }
  }
  if constexpr (REDUCE) {
    __syncthreads();
    if (t < 128) {
      float M = -1e30f;
#pragma unroll
      for (int c = 0; c < 8; ++c) M = fmaxf(M, rmaxL[c * 128 + t]);
      float S = 0.f;
#pragma unroll
      for (int c = 0; c < 8; ++c) S += rsumL[c * 128 + t] * __expf(rmaxL[c * 128 + t] - M);
      size_t rb = ((size_t)bz * gm + (tile_m >> 7)) * N + tile_n + t;
      red_max[rb] = M;
      red_sum[rb] = S;
    }
  }
}

// combine partials -> M, 1/Z per (b,col). grid: (cols/256, B)
__global__ __launch_bounds__(256) void colsm_combine(
    const float* __restrict__ red_max, const float* __restrict__ red_sum,
    float* __restrict__ Mv, float* __restrict__ Zinv, int cols, int nch)
{
  const int b = blockIdx.y;
  const int c = blockIdx.x * 256 + threadIdx.x;
  float M = -1e30f, Z = 0.f;
  for (int ch = 0; ch < nch; ++ch) {
    size_t o = ((size_t)b * nch + ch) * cols + c;
    float m = red_max[o], s = red_sum[o];
    float nm = fmaxf(M, m);
    Z = Z * __expf(M - nm) + s * __expf(m - nm);
    M = nm;
  }
  Mv[(size_t)b * cols + c] = M;
  Zinv[(size_t)b * cols + c] = 1.f / Z;
}

// emit bf16 probs = exp(scores - M[col]) * Zinv[col]
__global__ __launch_bounds__(256) void colsm_emit_bf16(
    const ushort* __restrict__ X, ushort* __restrict__ P,
    const float* __restrict__ Mv, const float* __restrict__ Zinv,
    int rows, int cols, int rpc)
{
  const int b = blockIdx.y;
  const int ch = blockIdx.z;
  const size_t base = (size_t)b * rows * cols;
  const int c4 = (blockIdx.x * 256 + threadIdx.x) * 4;
  const int r0 = ch * rpc;
  float M[4], Zi[4];
#pragma unroll
  for (int i = 0; i < 4; ++i) {
    M[i] = Mv[(size_t)b * cols + c4 + i];
    Zi[i] = Zinv[(size_t)b * cols + c4 + i];
  }
  for (int r = r0; r < r0 + rpc; ++r) {
    size_t o = base + (size_t)r * cols + c4;
    ushort4 u = *(const ushort4*)(X + o);
    ushort4 w;
    w.x = f2bf(__expf(bf2f(u.x) - M[0]) * Zi[0]);
    w.y = f2bf(__expf(bf2f(u.y) - M[1]) * Zi[1]);
    w.z = f2bf(__expf(bf2f(u.z) - M[2]) * Zi[2]);
    w.w = f2bf(__expf(bf2f(u.w) - M[3]) * Zi[3]);
    *(ushort4*)(P + o) = w;
  }
}

// final: out1 = softmax(attn over rows), out0 = attn + residual. attn is bf16.
__global__ __launch_bounds__(256) void final_emit(
    const ushort* __restrict__ attnB, const float* __restrict__ q,
    float* __restrict__ out0, float* __restrict__ out1,
    const float* __restrict__ Mv, const float* __restrict__ Zinv,
    int rows, int cols, int rpc)
{
  const int b = blockIdx.y;
  const int ch = blockIdx.z;
  const size_t base = (size_t)b * rows * cols;
  const int c4 = (blockIdx.x * 256 + threadIdx.x) * 4;
  const int r0 = ch * rpc;
  float M[4], Zi[4];
#pragma unroll
  for (int i = 0; i < 4; ++i) {
    M[i] = Mv[(size_t)b * cols + c4 + i];
    Zi[i] = Zinv[(size_t)b * cols + c4 + i];
  }
  for (int r = r0; r < r0 + rpc; ++r) {
    size_t o = base + (size_t)r * cols + c4;
    ushort4 u = *(const ushort4*)(attnB + o);
    float4 qv = *(const float4*)(q + o);
    float a0 = bf2f(u.x), a1 = bf2f(u.y), a2 = bf2f(u.z), a3 = bf2f(u.w);
    float4 w, s;
    w.x = __expf(a0 - M[0]) * Zi[0];
    w.y = __expf(a1 - M[1]) * Zi[1];
    w.z = __expf(a2 - M[2]) * Zi[2];
    w.w = __expf(a3 - M[3]) * Zi[3];
    s.x = a0 + qv.x; s.y = a1 + qv.y; s.z = a2 + qv.z; s.w = a3 + qv.w;
    *(float4*)(out1 + o) = w;
    *(float4*)(out0 + o) = s;
  }
}

extern "C" void kernel_launch(void* const* d_in, const int* in_sizes, int n_in,
                              void* d_out, int out_size, void* d_ws, size_t ws_size,
                              hipStream_t stream) {
  const float* q  = (const float*)d_in[0];
  const float* k  = (const float*)d_in[1];
  const float* v  = (const float*)d_in[2];
  const float* Wq = (const float*)d_in[3];
  const float* bq = (const float*)d_in[4];
  const float* Wk = (const float*)d_in[5];
  const float* bk = (const float*)d_in[6];
  const float* Wv = (const float*)d_in[7];
  const float* bv = (const float*)d_in[8];
  float* out = (float*)d_out;

  const int B = 8, S = 2048, D = 1024;
  const long BS = (long)B * S;
  const long nQKV = BS * D;
  const long nW = (long)D * D;

  // ---- workspace map (160 MiB) ----
  //  [0,32M)    qp bf16                 -> probs (lower half) after scores GEMM
  //  [32,64M)   kp bf16                 -> probs (upper half)
  //  [64,96M)   vpT bf16 [b][e][s]
  //  [96,160M)  Wqb/Wkb/Wvb (early) -> scores bf16 [b][q][k]
  //             -> attn bf16 [96,128M) + red_f/Mf/Zf [128M+) after emit
  char* ws = (char*)d_ws;
  ushort* qp     = (ushort*)ws;
  ushort* kp     = (ushort*)(ws + (32ull << 20));
  ushort* vpT    = (ushort*)(ws + (64ull << 20));
  ushort* Wqb    = (ushort*)(ws + (96ull << 20));   // 2MB, dead before scores GEMM
  ushort* Wkb    = Wqb + nW;
  ushort* Wvb    = Wkb + nW;
  ushort* scores = (ushort*)(ws + (96ull << 20));
  ushort* probs  = (ushort*)ws;                      // 64MB over qp+kp
  ushort* attnB  = (ushort*)(ws + (96ull << 20));    // 32MB over scores lower
  float* red_f_max = (float*)(ws + (128ull << 20));  // 512KB
  float* red_f_sum = (float*)(ws + (129ull << 20));
  float* Mf        = (float*)(ws + (130ull << 20));  // 32KB
  float* Zf        = (float*)(ws + (131ull << 20));

  // scores-softmax partials in d_out (free until final_emit)
  float* red_s_max = (float*)d_out;                              // 2MB
  float* red_s_sum = (float*)((char*)d_out + (2ull << 20));
  float* Ms        = (float*)((char*)d_out + (4ull << 20));      // 64KB
  float* Zs        = (float*)((char*)d_out + (4ull << 20) + 65536);

  const int GM_CH = 16;   // reduce chunks = gm of scores/PV GEMMs

  // ---- weight conversions (tiny) ----
  {
    int n4 = (int)(nW / 4);
    cvt_f32_bf16<<<dim3((n4 + 255) / 256), 256, 0, stream>>>((const float4*)Wq, (ushort4*)Wqb, n4);
    cvt_f32_bf16<<<dim3((n4 + 255) / 256), 256, 0, stream>>>((const float4*)Wk, (ushort4*)Wkb, n4);
    cvt_f32_bf16<<<dim3((n4 + 255) / 256), 256, 0, stream>>>((const float4*)Wv, (ushort4*)Wvb, n4);
  }

  // qp[m][e] = q[m][:]·Wq[e][:] + bq[e]   (A = q fp32 reg-staged)
  gemm_bt<1, 1, 0, 1, 0, 0><<<dim3(128 * 8), 256, 0, stream>>>(
      q, Wqb, qp, bq, nullptr, nullptr, D, D, 0, 0, 0, 1.f, 128, 8);
  gemm_bt<1, 1, 0, 1, 0, 0><<<dim3(128 * 8), 256, 0, stream>>>(
      k, Wkb, kp, bk, nullptr, nullptr, D, D, 0, 0, 0, 1.f, 128, 8);
  // vpT[b][e][s] = Wv[e][:]·v[b][s][:] + bv[e]  (B = v fp32 reg-staged)
  gemm_bt<1, 2, 0, 0, 1, 0><<<dim3(8 * 16 * B), 256, 0, stream>>>(
      Wvb, v, vpT, bv, nullptr, nullptr, S, D, 0, (long)S * D, (long)D * S, 1.f, 8, 16);
  // scores = qp·kp^T / 1024, + fused softmax pass1 partials
  gemm_bt<1, 0, 1, 0, 0, 1><<<dim3(16 * 16 * B), 256, 0, stream>>>(
      qp, kp, scores, nullptr, red_s_max, red_s_sum,
      S, D, (long)S * D, (long)S * D, (long)S * S, 1.f / 1024.f, 16, 16);

  colsm_combine<<<dim3(S / 256, B), 256, 0, stream>>>(red_s_max, red_s_sum, Ms, Zs, S, GM_CH);
  colsm_emit_bf16<<<dim3(S / 1024, B, 128), 256, 0, stream>>>(scores, probs, Ms, Zs, S, S, 16);

  // attn = probs·vpT^T (bf16 out) + fused final-softmax pass1 partials
  gemm_bt<1, 0, 0, 0, 0, 1><<<dim3(16 * 8 * B), 256, 0, stream>>>(
      probs, vpT, attnB, nullptr, red_f_max, red_f_sum,
      D, S, (long)S * S, (long)D * S, (long)S * D, 1.f, 16, 8);

  colsm_combine<<<dim3(D / 256, B), 256, 0, stream>>>(red_f_max, red_f_sum, Mf, Zf, D, GM_CH);
  final_emit<<<dim3(1, B, 128), 256, 0, stream>>>(attnB, q, out, out + nQKV, Mf, Zf, S, D, 16);

  (void)in_sizes; (void)n_in; (void)out_size; (void)ws_size;
}

// Round 5
// 532.968 us; speedup vs baseline: 1.1020x; 1.0462x over previous
//
#include <hip/hip_runtime.h>

typedef __attribute__((ext_vector_type(8))) __bf16 bf16x8;
typedef __attribute__((ext_vector_type(4))) float f32x4;

__device__ __forceinline__ ushort f2bf(float f) {
  union { float f; unsigned u; } x; x.f = f;
  unsigned r = x.u + 0x7FFFu + ((x.u >> 16) & 1u);
  return (ushort)(r >> 16);
}
__device__ __forceinline__ float bf2f(ushort u) {
  union { unsigned u; float f; } x; x.u = ((unsigned)u) << 16;
  return x.f;
}

__device__ __forceinline__ void gload_lds16(const void* g, void* l) {
  __builtin_amdgcn_global_load_lds(
      (const __attribute__((address_space(1))) void*)g,
      (__attribute__((address_space(3))) void*)l, 16, 0, 0);
}

// ---------------- fp32 -> bf16 convert ----------------
__global__ __launch_bounds__(256) void cvt_f32_bf16(const float4* __restrict__ in,
                                                    ushort4* __restrict__ out, int n4) {
  int i = blockIdx.x * 256 + threadIdx.x;
  if (i >= n4) return;
  float4 v = in[i];
  ushort4 o;
  o.x = f2bf(v.x); o.y = f2bf(v.y); o.z = f2bf(v.z); o.w = f2bf(v.w);
  out[i] = o;
}

// ---------------- B^T-form bf16 MFMA GEMM, 3-buffer counted-vmcnt pipeline ----------------
// C[m,n] = (sum_k A[m,k]*B[n,k]) * (SCALED?scale:1) + bias
// Pipeline: iter kt stages tile kt+2 (4 gload_lds), computes tile kt, then
// waits vmcnt(4) (= tile kt+1 landed; kt+2 stays in flight) + s_barrier.
// No vmcnt(0) drain in the main loop (T4). Only gload_lds ops use vmcnt in-loop.
// REDUCE: epilogue emits per-tile column (max,sumexp) partials (softmax pass1).
template<int OUT_BF16, int BIAS_MODE, int SCALED, int REDUCE>
__global__ __launch_bounds__(256) void gemm_bt(
    const ushort* __restrict__ A, const ushort* __restrict__ B,
    void* __restrict__ Cv, const float* __restrict__ bias,
    float* __restrict__ red_max, float* __restrict__ red_sum,
    int N, int K, long sA, long sB, long sC, float scale, int gm, int gn)
{
  __shared__ ushort At[3][128 * 32];
  __shared__ ushort Bt[3][128 * 32];

  // ---- tile decode: bijective XCD swizzle + banded order ----
  const int nwg = gridDim.x;
  const int wg = blockIdx.x;
  const int cpx = nwg >> 3;
  const int wid = (wg & 7) * cpx + (wg >> 3);
  const int tiles = gm * gn;
  const int bz = wid / tiles;
  const int t2 = wid - bz * tiles;
  const int band = t2 / (gm << 2);
  const int r2 = t2 - band * (gm << 2);
  const int tile_m = (r2 >> 2) * 128;
  const int tile_n = ((band << 2) + (r2 & 3)) * 128;

  const ushort* Ab = A + (size_t)bz * sA;
  const ushort* Bb = B + (size_t)bz * sB;
  const int t = threadIdx.x;
  const int lane = t & 63;
  const int m_off = ((t >> 6) >> 1) * 64;
  const int n_off = ((t >> 6) & 1) * 64;

  f32x4 acc[4][4] = {};

  // stage one 128x32 bf16 tile of A and B into buffer p (4 gload_lds/thread)
#define STAGE(p, k0)                                                                     \
  do {                                                                                   \
    for (int i = 0; i < 2; ++i) {                                                        \
      int o = t * 16 + i * 4096;                                                         \
      int r = o >> 6, cb = o & 63;                                                       \
      gload_lds16((const char*)(Ab + (size_t)(tile_m + r) * K + (k0)) + cb,              \
                  (char*)&At[p][0] + o);                                                 \
      gload_lds16((const char*)(Bb + (size_t)(tile_n + r) * K + (k0)) + cb,              \
                  (char*)&Bt[p][0] + o);                                                 \
    }                                                                                    \
  } while (0)

#define COMPUTE(p)                                                                       \
  do {                                                                                   \
    bf16x8 af[4], bfr[4];                                                                \
    _Pragma("unroll")                                                                    \
    for (int x = 0; x < 4; ++x) {                                                        \
      af[x]  = *(const bf16x8*)&At[p][(m_off + x * 16 + (lane & 15)) * 32 + (lane >> 4) * 8]; \
      bfr[x] = *(const bf16x8*)&Bt[p][(n_off + x * 16 + (lane & 15)) * 32 + (lane >> 4) * 8]; \
    }                                                                                    \
    _Pragma("unroll")                                                                    \
    for (int mi = 0; mi < 4; ++mi)                                                       \
      _Pragma("unroll")                                                                  \
      for (int ni = 0; ni < 4; ++ni)                                                     \
        acc[mi][ni] = __builtin_amdgcn_mfma_f32_16x16x32_bf16(af[mi], bfr[ni], acc[mi][ni], 0, 0, 0); \
  } while (0)

  // ---- prologue: stage tiles 0,1 ----
  STAGE(0, 0);
  STAGE(1, 32);
  asm volatile("s_waitcnt vmcnt(4)" ::: "memory");   // tile 0 landed (tile 1 in flight)
  __builtin_amdgcn_s_barrier();
  __builtin_amdgcn_sched_barrier(0);

  const int KT = K >> 5;
  int p = 0, ps = 2;
  for (int kt = 0; kt < KT - 2; ++kt) {
    STAGE(ps, (kt + 2) * 32);
    COMPUTE(p);
    __builtin_amdgcn_sched_barrier(0);
    asm volatile("s_waitcnt vmcnt(4)" ::: "memory"); // tile kt+1 landed; kt+2 in flight
    __builtin_amdgcn_s_barrier();
    __builtin_amdgcn_sched_barrier(0);
    p = (p == 2) ? 0 : p + 1;
    ps = (ps == 2) ? 0 : ps + 1;
  }
  // tail: tiles KT-2, KT-1 (no more staging)
  COMPUTE(p);
  __builtin_amdgcn_sched_barrier(0);
  asm volatile("s_waitcnt vmcnt(0)" ::: "memory");   // tile KT-1 landed
  __builtin_amdgcn_s_barrier();
  __builtin_amdgcn_sched_barrier(0);
  p = (p == 2) ? 0 : p + 1;
  COMPUTE(p);
#undef STAGE
#undef COMPUTE

  // ---- epilogue ----
  float* rmaxL = (float*)&At[0][0];      // [8][128] alias (REDUCE only)
  float* rsumL = rmaxL + 1024;
  if constexpr (REDUCE) __syncthreads();  // all LDS frag reads done before alias write

  const int r0 = tile_m + m_off + ((lane >> 4) * 4);
  const int c0 = tile_n + n_off + (lane & 15);
  const int contrib = (m_off >> 6) * 4 + (lane >> 4);   // 0..7
#pragma unroll
  for (int ni = 0; ni < 4; ++ni) {
    const int cc = c0 + ni * 16;
    float bc = 0.f;
    if (BIAS_MODE == 1) bc = bias[cc];
    float vals[16];
    float mx = -1e30f;
#pragma unroll
    for (int mi = 0; mi < 4; ++mi) {
#pragma unroll
      for (int j = 0; j < 4; ++j) {
        int rr = r0 + mi * 16 + j;
        float val = acc[mi][ni][j];
        if (SCALED) val *= scale;
        if (BIAS_MODE == 1) val += bc;
        else if (BIAS_MODE == 2) val += bias[rr];
        if (REDUCE) { vals[mi * 4 + j] = val; mx = fmaxf(mx, val); }
        size_t idx = (size_t)bz * sC + (size_t)rr * N + cc;
        if (OUT_BF16) ((ushort*)Cv)[idx] = f2bf(val);
        else          ((float*)Cv)[idx] = val;
      }
    }
    if constexpr (REDUCE) {
      float sm = 0.f;
#pragma unroll
      for (int x = 0; x < 16; ++x) sm += __expf(vals[x] - mx);
      int colloc = n_off + ni * 16 + (lane & 15);
      rmaxL[contrib * 128 + colloc] = mx;
      rsumL[contrib * 128 + colloc] = sm;
    }
  }
  if constexpr (REDUCE) {
    __syncthreads();
    if (t < 128) {
      float M = -1e30f;
#pragma unroll
      for (int c = 0; c < 8; ++c) M = fmaxf(M, rmaxL[c * 128 + t]);
      float S = 0.f;
#pragma unroll
      for (int c = 0; c < 8; ++c) S += rsumL[c * 128 + t] * __expf(rmaxL[c * 128 + t] - M);
      size_t rb = ((size_t)bz * gm + (tile_m >> 7)) * N + tile_n + t;
      red_max[rb] = M;
      red_sum[rb] = S;
    }
  }
}

// combine partials -> M, 1/Z per (b,col). grid: (cols/256, B)
__global__ __launch_bounds__(256) void colsm_combine(
    const float* __restrict__ red_max, const float* __restrict__ red_sum,
    float* __restrict__ Mv, float* __restrict__ Zinv, int cols, int nch)
{
  const int b = blockIdx.y;
  const int c = blockIdx.x * 256 + threadIdx.x;
  float M = -1e30f, Z = 0.f;
  for (int ch = 0; ch < nch; ++ch) {
    size_t o = ((size_t)b * nch + ch) * cols + c;
    float m = red_max[o], s = red_sum[o];
    float nm = fmaxf(M, m);
    Z = Z * __expf(M - nm) + s * __expf(m - nm);
    M = nm;
  }
  Mv[(size_t)b * cols + c] = M;
  Zinv[(size_t)b * cols + c] = 1.f / Z;
}

// emit bf16 probs = exp(scores - M[col]) * Zinv[col]
__global__ __launch_bounds__(256) void colsm_emit_bf16(
    const ushort* __restrict__ X, ushort* __restrict__ P,
    const float* __restrict__ Mv, const float* __restrict__ Zinv,
    int rows, int cols, int rpc)
{
  const int b = blockIdx.y;
  const int ch = blockIdx.z;
  const size_t base = (size_t)b * rows * cols;
  const int c4 = (blockIdx.x * 256 + threadIdx.x) * 4;
  const int r0 = ch * rpc;
  float M[4], Zi[4];
#pragma unroll
  for (int i = 0; i < 4; ++i) {
    M[i] = Mv[(size_t)b * cols + c4 + i];
    Zi[i] = Zinv[(size_t)b * cols + c4 + i];
  }
  for (int r = r0; r < r0 + rpc; ++r) {
    size_t o = base + (size_t)r * cols + c4;
    ushort4 u = *(const ushort4*)(X + o);
    ushort4 w;
    w.x = f2bf(__expf(bf2f(u.x) - M[0]) * Zi[0]);
    w.y = f2bf(__expf(bf2f(u.y) - M[1]) * Zi[1]);
    w.z = f2bf(__expf(bf2f(u.z) - M[2]) * Zi[2]);
    w.w = f2bf(__expf(bf2f(u.w) - M[3]) * Zi[3]);
    *(ushort4*)(P + o) = w;
  }
}

// final: out1 = softmax(attn over rows), out0 = attn + residual. attn is bf16.
__global__ __launch_bounds__(256) void final_emit(
    const ushort* __restrict__ attnB, const float* __restrict__ q,
    float* __restrict__ out0, float* __restrict__ out1,
    const float* __restrict__ Mv, const float* __restrict__ Zinv,
    int rows, int cols, int rpc)
{
  const int b = blockIdx.y;
  const int ch = blockIdx.z;
  const size_t base = (size_t)b * rows * cols;
  const int c4 = (blockIdx.x * 256 + threadIdx.x) * 4;
  const int r0 = ch * rpc;
  float M[4], Zi[4];
#pragma unroll
  for (int i = 0; i < 4; ++i) {
    M[i] = Mv[(size_t)b * cols + c4 + i];
    Zi[i] = Zinv[(size_t)b * cols + c4 + i];
  }
  for (int r = r0; r < r0 + rpc; ++r) {
    size_t o = base + (size_t)r * cols + c4;
    ushort4 u = *(const ushort4*)(attnB + o);
    float4 qv = *(const float4*)(q + o);
    float a0 = bf2f(u.x), a1 = bf2f(u.y), a2 = bf2f(u.z), a3 = bf2f(u.w);
    float4 w, s;
    w.x = __expf(a0 - M[0]) * Zi[0];
    w.y = __expf(a1 - M[1]) * Zi[1];
    w.z = __expf(a2 - M[2]) * Zi[2];
    w.w = __expf(a3 - M[3]) * Zi[3];
    s.x = a0 + qv.x; s.y = a1 + qv.y; s.z = a2 + qv.z; s.w = a3 + qv.w;
    *(float4*)(out1 + o) = w;
    *(float4*)(out0 + o) = s;
  }
}

extern "C" void kernel_launch(void* const* d_in, const int* in_sizes, int n_in,
                              void* d_out, int out_size, void* d_ws, size_t ws_size,
                              hipStream_t stream) {
  const float* q  = (const float*)d_in[0];
  const float* k  = (const float*)d_in[1];
  const float* v  = (const float*)d_in[2];
  const float* Wq = (const float*)d_in[3];
  const float* bq = (const float*)d_in[4];
  const float* Wk = (const float*)d_in[5];
  const float* bk = (const float*)d_in[6];
  const float* Wv = (const float*)d_in[7];
  const float* bv = (const float*)d_in[8];
  float* out = (float*)d_out;

  const int B = 8, S = 2048, D = 1024;
  const long BS = (long)B * S;
  const long nQKV = BS * D;
  const long nW = (long)D * D;

  // ---- d_out as staging (134 MB):
  //  [0,32M) qb, [32,64M) kb, [64,96M) vb  (dead after proj/vpT GEMMs)
  //  [96,100.2M) red_s partials + Ms/Zs  (written by scores GEMM, after staging dead)
  //  final_emit overwrites all of d_out at the end.
  ushort* qb = (ushort*)d_out;
  ushort* kb = qb + nQKV;
  ushort* vb = kb + nQKV;
  float* red_s_max = (float*)((char*)d_out + (96ull << 20));       // 2MB
  float* red_s_sum = (float*)((char*)d_out + (98ull << 20));       // 2MB
  float* Ms        = (float*)((char*)d_out + (100ull << 20));      // 64KB
  float* Zs        = (float*)((char*)d_out + (100ull << 20) + 65536);

  // ---- workspace map (<=132 MiB):
  //  [0,32M)   qp bf16            -> probs lower after scores
  //  [32,64M)  kp bf16            -> probs upper
  //  [64,96M)  vpT bf16 [b][e][s]
  //  [96,160M) Wqb/Wkb/Wvb (early) -> scores bf16 -> attnB bf16 [96,128M)
  //  [128M+)   red_f partials + Mf/Zf
  char* ws = (char*)d_ws;
  ushort* qp     = (ushort*)ws;
  ushort* kp     = (ushort*)(ws + (32ull << 20));
  ushort* vpT    = (ushort*)(ws + (64ull << 20));
  ushort* Wqb    = (ushort*)(ws + (96ull << 20));   // 2MB each, dead before scores
  ushort* Wkb    = Wqb + nW;
  ushort* Wvb    = Wkb + nW;
  ushort* scores = (ushort*)(ws + (96ull << 20));
  ushort* probs  = (ushort*)ws;
  ushort* attnB  = (ushort*)(ws + (96ull << 20));
  float* red_f_max = (float*)(ws + (128ull << 20));
  float* red_f_sum = (float*)(ws + (129ull << 20));
  float* Mf        = (float*)(ws + (130ull << 20));
  float* Zf        = (float*)(ws + (131ull << 20));

  const int GM_CH = 16;   // partial chunks per batch (= gm of scores/PV)

  auto cvt = [&](const float* src, ushort* dst, long n) {
    int n4 = (int)(n / 4);
    cvt_f32_bf16<<<dim3((n4 + 255) / 256), 256, 0, stream>>>((const float4*)src, (ushort4*)dst, n4);
  };
  cvt(Wq, Wqb, nW);
  cvt(Wk, Wkb, nW);
  cvt(Wv, Wvb, nW);
  cvt(q, qb, nQKV);
  cvt(k, kb, nQKV);
  cvt(v, vb, nQKV);

  // qp[m][e] = q[m][:]·Wq[e][:] + bq[e]
  gemm_bt<1, 1, 0, 0><<<dim3(128 * 8), 256, 0, stream>>>(
      qb, Wqb, qp, bq, nullptr, nullptr, D, D, 0, 0, 0, 1.f, 128, 8);
  gemm_bt<1, 1, 0, 0><<<dim3(128 * 8), 256, 0, stream>>>(
      kb, Wkb, kp, bk, nullptr, nullptr, D, D, 0, 0, 0, 1.f, 128, 8);
  // vpT[b][e][s] = Wv[e][:]·v[b][s][:] + bv[e]
  gemm_bt<1, 2, 0, 0><<<dim3(8 * 16 * B), 256, 0, stream>>>(
      Wvb, vb, vpT, bv, nullptr, nullptr, S, D, 0, (long)S * D, (long)D * S, 1.f, 8, 16);
  // scores = qp·kp^T / 1024 + fused softmax pass1 partials
  gemm_bt<1, 0, 1, 1><<<dim3(16 * 16 * B), 256, 0, stream>>>(
      qp, kp, scores, nullptr, red_s_max, red_s_sum,
      S, D, (long)S * D, (long)S * D, (long)S * S, 1.f / 1024.f, 16, 16);

  colsm_combine<<<dim3(S / 256, B), 256, 0, stream>>>(red_s_max, red_s_sum, Ms, Zs, S, GM_CH);
  colsm_emit_bf16<<<dim3(S / 1024, B, 128), 256, 0, stream>>>(scores, probs, Ms, Zs, S, S, 16);

  // attn = probs·vpT^T (bf16) + fused final-softmax pass1 partials
  gemm_bt<1, 0, 0, 1><<<dim3(16 * 8 * B), 256, 0, stream>>>(
      probs, vpT, attnB, nullptr, red_f_max, red_f_sum,
      D, S, (long)S * S, (long)D * S, (long)S * D, 1.f, 16, 8);

  colsm_combine<<<dim3(D / 256, B), 256, 0, stream>>>(red_f_max, red_f_sum, Mf, Zf, D, GM_CH);
  final_emit<<<dim3(1, B, 128), 256, 0, stream>>>(attnB, q, out, out + nQKV, Mf, Zf, S, D, 16);

  (void)in_sizes; (void)n_in; (void)out_size; (void)ws_size;
}

// Round 6
// 457.419 us; speedup vs baseline: 1.2840x; 1.1652x over previous
//
#include <hip/hip_runtime.h>

typedef __attribute__((ext_vector_type(8))) __bf16 bf16x8;
typedef __attribute__((ext_vector_type(4))) float f32x4;

__device__ __forceinline__ ushort f2bf(float f) {
  union { float f; unsigned u; } x; x.f = f;
  unsigned r = x.u + 0x7FFFu + ((x.u >> 16) & 1u);
  return (ushort)(r >> 16);
}
__device__ __forceinline__ float bf2f(ushort u) {
  union { unsigned u; float f; } x; x.u = ((unsigned)u) << 16;
  return x.f;
}

__device__ __forceinline__ void gload_lds16(const void* g, void* l) {
  __builtin_amdgcn_global_load_lds(
      (const __attribute__((address_space(1))) void*)g,
      (__attribute__((address_space(3))) void*)l, 16, 0, 0);
}

// ---------------- fp32 -> bf16 convert ----------------
__global__ __launch_bounds__(256) void cvt_f32_bf16(const float4* __restrict__ in,
                                                    ushort4* __restrict__ out, int n4) {
  int i = blockIdx.x * 256 + threadIdx.x;
  if (i >= n4) return;
  float4 v = in[i];
  ushort4 o;
  o.x = f2bf(v.x); o.y = f2bf(v.y); o.z = f2bf(v.z); o.w = f2bf(v.w);
  out[i] = o;
}

// ================= 256x256 8-wave phase-split bf16 GEMM (B^T form) =================
// C[m,n] = (sum_k A[m,k]*B[n,k]) * (SCALED?scale:1) + bias
// 512 threads = 8 waves (2 m-waves x 4 n-waves), per-wave output 128x64.
// BK=64, double-buffered 128KiB dynamic LDS, frag-major chunk layout:
//   chunk(rowblk,kk) = 1KB holding lane l's bf16x8 at (rowblk*16+(l&15), kk*32+(l>>4)*8)
//   -> ds_read_b128 at base+lane*16: zero bank conflicts; gload_lds dest linear.
// 4 phases per K-tile: {ds_read subtile | stage 2 gload_lds | [vmcnt(4)] | bar |
//   lgkmcnt(0) | setprio(1) 16 MFMA setprio(0) | bar}; vmcnt never 0 in steady loop.
// Staging slots deadline-ordered: ph1:A-half0' ph2:B-half0' ph3:B-half1' ph4:A-half1'.
// Per-wave outstanding ledger (pairs): entry [Bh1,Ah1]=4; ph2 wait vmcnt(4)->Bh1(cur)
// landed; ph3 wait -> Ah1(cur); ph4 (post slot4 issue, 8 out) wait -> next Ah0,Bh0.
// REDUCE: fused column-softmax pass1 -> red_max/red_sum[bz*gm + tile_m/256][N].
template<int OUT_BF16, int BIAS_MODE, int SCALED, int REDUCE>
__global__ __launch_bounds__(512, 2) void gemm256(
    const ushort* __restrict__ A, const ushort* __restrict__ B,
    void* __restrict__ Cv, const float* __restrict__ bias,
    float* __restrict__ red_max, float* __restrict__ red_sum,
    int N, int K, long sA, long sB, long sC, float scale, int gm, int gn)
{
  extern __shared__ ushort lds[];   // 131072 B: A: [2][16384], B at +32768: [2][16384]

  // ---- tile decode: bijective XCD swizzle + banded order ----
  const int nwg = gridDim.x;
  const int wg = blockIdx.x;
  const int cpx = nwg >> 3;
  const int wid_ = (wg & 7) * cpx + (wg >> 3);
  const int tiles = gm * gn;
  const int bz = wid_ / tiles;
  const int t2 = wid_ - bz * tiles;
  const int band = t2 / (gm << 2);
  const int r2 = t2 - band * (gm << 2);
  const int tile_m = (r2 >> 2) * 256;
  const int tile_n = ((band << 2) + (r2 & 3)) * 256;

  const ushort* Ab = A + (size_t)bz * sA;
  const ushort* Bb = B + (size_t)bz * sB;
  const int t = threadIdx.x;
  const int lane = t & 63;
  const int w = t >> 6;          // wave 0..7
  const int wr = w >> 2;         // 0..1
  const int wc = w & 3;          // 0..3

  f32x4 acc[8][4] = {};
  bf16x8 aA[4][2], bB[4][2];

#define LDA(c, q)                                                                     \
  _Pragma("unroll") for (int mi = 0; mi < 4; ++mi)                                    \
  _Pragma("unroll") for (int kk = 0; kk < 2; ++kk)                                    \
    aA[mi][kk] = *(const bf16x8*)&lds[(c) * 16384 +                                   \
        ((wr * 8 + (q) * 4 + mi) * 2 + kk) * 512 + lane * 8];

#define LDB(c, h)                                                                     \
  _Pragma("unroll") for (int nf = 0; nf < 2; ++nf)                                    \
  _Pragma("unroll") for (int kk = 0; kk < 2; ++kk)                                    \
    bB[(h) * 2 + nf][kk] = *(const bf16x8*)&lds[32768 + (c) * 16384 +                 \
        ((wc * 4 + (h) * 2 + nf) * 2 + kk) * 512 + lane * 8];

#define STAGE_A(c, k0, q)                                                             \
  _Pragma("unroll") for (int o = 0; o < 2; ++o) {                                     \
    int g = w * 2 + o;                                                                \
    int rowblk = (g >> 3) * 8 + (q) * 4 + ((g >> 1) & 3);                             \
    int kk = g & 1;                                                                   \
    gload_lds16(Ab + (size_t)(tile_m + rowblk * 16 + (lane & 15)) * K +               \
                    (k0) + kk * 32 + (lane >> 4) * 8,                                 \
                &lds[(c) * 16384 + (rowblk * 2 + kk) * 512]);                         \
  }

#define STAGE_B(c, k0, q)                                                             \
  _Pragma("unroll") for (int o = 0; o < 2; ++o) {                                     \
    int g = w * 2 + o;                                                                \
    int rowblk = (g >> 2) * 4 + (q) * 2 + ((g >> 1) & 1);                             \
    int kk = g & 1;                                                                   \
    gload_lds16(Bb + (size_t)(tile_n + rowblk * 16 + (lane & 15)) * K +               \
                    (k0) + kk * 32 + (lane >> 4) * 8,                                 \
                &lds[32768 + (c) * 16384 + (rowblk * 2 + kk) * 512]);                 \
  }

#define MFMA_PH(MB, NB)                                                               \
  _Pragma("unroll") for (int kk = 0; kk < 2; ++kk)                                    \
  _Pragma("unroll") for (int mi = 0; mi < 4; ++mi)                                    \
  _Pragma("unroll") for (int nf = 0; nf < 2; ++nf)                                    \
    acc[(MB) + mi][(NB) + nf] = __builtin_amdgcn_mfma_f32_16x16x32_bf16(              \
        aA[mi][kk], bB[(NB) + nf][kk], acc[(MB) + mi][(NB) + nf], 0, 0, 0);

#define ITER(c, DOSTAGE, k0n, W2, W3, W4)                                             \
  {                                                                                   \
    /* ---- phase 1: C quadrant m0-3 x n0-1 ---- */                                   \
    LDA(c, 0);                                                                        \
    LDB(c, 0);                                                                        \
    if (DOSTAGE) { STAGE_A((c) ^ 1, k0n, 0); }                                        \
    __builtin_amdgcn_s_barrier();                                                     \
    asm volatile("s_waitcnt lgkmcnt(0)" ::: "memory");                                \
    __builtin_amdgcn_sched_barrier(0);                                                \
    __builtin_amdgcn_s_setprio(1);                                                    \
    MFMA_PH(0, 0);                                                                    \
    __builtin_amdgcn_s_setprio(0);                                                    \
    __builtin_amdgcn_s_barrier();                                                     \
    /* ---- phase 2: m0-3 x n2-3 ---- */                                              \
    LDB(c, 1);                                                                        \
    if (DOSTAGE) { STAGE_B((c) ^ 1, k0n, 0); }                                        \
    asm volatile(W2 ::: "memory");                                                    \
    __builtin_amdgcn_s_barrier();                                                     \
    asm volatile("s_waitcnt lgkmcnt(0)" ::: "memory");                                \
    __builtin_amdgcn_sched_barrier(0);                                                \
    __builtin_amdgcn_s_setprio(1);                                                    \
    MFMA_PH(0, 2);                                                                    \
    __builtin_amdgcn_s_setprio(0);                                                    \
    __builtin_amdgcn_s_barrier();                                                     \
    /* ---- phase 3: m4-7 x n0-1 ---- */                                              \
    LDA(c, 1);                                                                        \
    if (DOSTAGE) { STAGE_B((c) ^ 1, k0n, 1); }                                        \
    asm volatile(W3 ::: "memory");                                                    \
    __builtin_amdgcn_s_barrier();                                                     \
    asm volatile("s_waitcnt lgkmcnt(0)" ::: "memory");                                \
    __builtin_amdgcn_sched_barrier(0);                                                \
    __builtin_amdgcn_s_setprio(1);                                                    \
    MFMA_PH(4, 0);                                                                    \
    __builtin_amdgcn_s_setprio(0);                                                    \
    __builtin_amdgcn_s_barrier();                                                     \
    /* ---- phase 4: m4-7 x n2-3 ---- */                                              \
    if (DOSTAGE) { STAGE_A((c) ^ 1, k0n, 1); asm volatile(W4 ::: "memory"); }         \
    __builtin_amdgcn_s_barrier();                                                     \
    __builtin_amdgcn_sched_barrier(0);                                                \
    __builtin_amdgcn_s_setprio(1);                                                    \
    MFMA_PH(4, 2);                                                                    \
    __builtin_amdgcn_s_setprio(0);                                                    \
    __builtin_amdgcn_s_barrier();                                                     \
  }

  // ---- prologue: stage K-tile 0 into buf 0, slots in deadline order ----
  STAGE_A(0, 0, 0);
  STAGE_B(0, 0, 0);
  STAGE_B(0, 0, 1);
  STAGE_A(0, 0, 1);
  asm volatile("s_waitcnt vmcnt(4)" ::: "memory");  // slots 1,2 landed; 3,4 in flight
  __builtin_amdgcn_s_barrier();

  const int KT = K >> 6;
  for (int tt = 0; tt < KT - 1; ++tt) {
    const int c = tt & 1;
    const int k0n = (tt + 1) << 6;
    ITER(c, true, k0n,
         "s_waitcnt vmcnt(4)", "s_waitcnt vmcnt(4)", "s_waitcnt vmcnt(4)");
  }
  // peeled last K-tile: no staging; entry outstanding = [Bh1(cur), Ah1(cur)] = 4
  ITER(((KT - 1) & 1), false, 0,
       "s_waitcnt vmcnt(2)", "s_waitcnt vmcnt(0)", "s_nop 0");

#undef ITER
#undef MFMA_PH
#undef STAGE_A
#undef STAGE_B
#undef LDA
#undef LDB

  // ---- epilogue: C write (+ fused column-softmax pass1) ----
  float* mb = (float*)lds;          // [2][256] per-wave-half column max
  float* sb = (float*)lds + 512;    // [2][256] per-wave-half column sumexp
  const int cc0 = tile_n + wc * 64 + (lane & 15);
#pragma unroll
  for (int nf = 0; nf < 4; ++nf) {
    const int cc = cc0 + nf * 16;
    float bcn = 0.f;
    if (BIAS_MODE == 1) bcn = bias[cc];
    float mx = -1e30f;
#pragma unroll
    for (int mi = 0; mi < 8; ++mi) {
#pragma unroll
      for (int j = 0; j < 4; ++j) {
        int rr = tile_m + wr * 128 + mi * 16 + ((lane >> 4) << 2) + j;
        float val = acc[mi][nf][j];
        if (SCALED) val *= scale;
        if (BIAS_MODE == 1) val += bcn;
        else if (BIAS_MODE == 2) val += bias[rr];
        if (REDUCE) mx = fmaxf(mx, val);
        size_t idx = (size_t)bz * sC + (size_t)rr * N + cc;
        if (OUT_BF16) ((ushort*)Cv)[idx] = f2bf(val);
        else          ((float*)Cv)[idx] = val;
      }
    }
    if constexpr (REDUCE) {
      float m1 = fmaxf(mx, __shfl_xor(mx, 16));
      float M = fmaxf(m1, __shfl_xor(m1, 32));
      float sm = 0.f;
#pragma unroll
      for (int mi = 0; mi < 8; ++mi) {
#pragma unroll
        for (int j = 0; j < 4; ++j) {
          int rr = tile_m + wr * 128 + mi * 16 + ((lane >> 4) << 2) + j;
          float val = acc[mi][nf][j];
          if (SCALED) val *= scale;
          if (BIAS_MODE == 1) val += bcn;
          else if (BIAS_MODE == 2) val += bias[rr];
          sm += __expf(val - M);
        }
      }
      float s1 = sm + __shfl_xor(sm, 16);
      float Ss = s1 + __shfl_xor(s1, 32);
      if ((lane >> 4) == nf) {
        mb[wr * 256 + wc * 64 + nf * 16 + (lane & 15)] = M;
        sb[wr * 256 + wc * 64 + nf * 16 + (lane & 15)] = Ss;
      }
    }
  }
  if constexpr (REDUCE) {
    __syncthreads();
    if (t < 256) {
      float m0 = mb[t], m1v = mb[256 + t];
      float M = fmaxf(m0, m1v);
      float Ss = sb[t] * __expf(m0 - M) + sb[256 + t] * __expf(m1v - M);
      size_t rb = ((size_t)bz * gm + (tile_m >> 8)) * N + tile_n + t;
      red_max[rb] = M;
      red_sum[rb] = Ss;
    }
  }
}

// combine partials -> M, 1/Z per (b,col). grid: (cols/256, B)
__global__ __launch_bounds__(256) void colsm_combine(
    const float* __restrict__ red_max, const float* __restrict__ red_sum,
    float* __restrict__ Mv, float* __restrict__ Zinv, int cols, int nch)
{
  const int b = blockIdx.y;
  const int c = blockIdx.x * 256 + threadIdx.x;
  float M = -1e30f, Z = 0.f;
  for (int ch = 0; ch < nch; ++ch) {
    size_t o = ((size_t)b * nch + ch) * cols + c;
    float m = red_max[o], s = red_sum[o];
    float nm = fmaxf(M, m);
    Z = Z * __expf(M - nm) + s * __expf(m - nm);
    M = nm;
  }
  Mv[(size_t)b * cols + c] = M;
  Zinv[(size_t)b * cols + c] = 1.f / Z;
}

// emit bf16 probs = exp(scores - M[col]) * Zinv[col]
__global__ __launch_bounds__(256) void colsm_emit_bf16(
    const ushort* __restrict__ X, ushort* __restrict__ P,
    const float* __restrict__ Mv, const float* __restrict__ Zinv,
    int rows, int cols, int rpc)
{
  const int b = blockIdx.y;
  const int ch = blockIdx.z;
  const size_t base = (size_t)b * rows * cols;
  const int c4 = (blockIdx.x * 256 + threadIdx.x) * 4;
  const int r0 = ch * rpc;
  float M[4], Zi[4];
#pragma unroll
  for (int i = 0; i < 4; ++i) {
    M[i] = Mv[(size_t)b * cols + c4 + i];
    Zi[i] = Zinv[(size_t)b * cols + c4 + i];
  }
  for (int r = r0; r < r0 + rpc; ++r) {
    size_t o = base + (size_t)r * cols + c4;
    ushort4 u = *(const ushort4*)(X + o);
    ushort4 wv;
    wv.x = f2bf(__expf(bf2f(u.x) - M[0]) * Zi[0]);
    wv.y = f2bf(__expf(bf2f(u.y) - M[1]) * Zi[1]);
    wv.z = f2bf(__expf(bf2f(u.z) - M[2]) * Zi[2]);
    wv.w = f2bf(__expf(bf2f(u.w) - M[3]) * Zi[3]);
    *(ushort4*)(P + o) = wv;
  }
}

// final: out1 = softmax(attn over rows), out0 = attn + residual. attn is bf16.
__global__ __launch_bounds__(256) void final_emit(
    const ushort* __restrict__ attnB, const float* __restrict__ q,
    float* __restrict__ out0, float* __restrict__ out1,
    const float* __restrict__ Mv, const float* __restrict__ Zinv,
    int rows, int cols, int rpc)
{
  const int b = blockIdx.y;
  const int ch = blockIdx.z;
  const size_t base = (size_t)b * rows * cols;
  const int c4 = (blockIdx.x * 256 + threadIdx.x) * 4;
  const int r0 = ch * rpc;
  float M[4], Zi[4];
#pragma unroll
  for (int i = 0; i < 4; ++i) {
    M[i] = Mv[(size_t)b * cols + c4 + i];
    Zi[i] = Zinv[(size_t)b * cols + c4 + i];
  }
  for (int r = r0; r < r0 + rpc; ++r) {
    size_t o = base + (size_t)r * cols + c4;
    ushort4 u = *(const ushort4*)(attnB + o);
    float4 qv = *(const float4*)(q + o);
    float a0 = bf2f(u.x), a1 = bf2f(u.y), a2 = bf2f(u.z), a3 = bf2f(u.w);
    float4 wv, s;
    wv.x = __expf(a0 - M[0]) * Zi[0];
    wv.y = __expf(a1 - M[1]) * Zi[1];
    wv.z = __expf(a2 - M[2]) * Zi[2];
    wv.w = __expf(a3 - M[3]) * Zi[3];
    s.x = a0 + qv.x; s.y = a1 + qv.y; s.z = a2 + qv.z; s.w = a3 + qv.w;
    *(float4*)(out1 + o) = wv;
    *(float4*)(out0 + o) = s;
  }
}

extern "C" void kernel_launch(void* const* d_in, const int* in_sizes, int n_in,
                              void* d_out, int out_size, void* d_ws, size_t ws_size,
                              hipStream_t stream) {
  const float* q  = (const float*)d_in[0];
  const float* k  = (const float*)d_in[1];
  const float* v  = (const float*)d_in[2];
  const float* Wq = (const float*)d_in[3];
  const float* bq = (const float*)d_in[4];
  const float* Wk = (const float*)d_in[5];
  const float* bk = (const float*)d_in[6];
  const float* Wv = (const float*)d_in[7];
  const float* bv = (const float*)d_in[8];
  float* out = (float*)d_out;

  const int B = 8, S = 2048, D = 1024;
  const long BS = (long)B * S;
  const long nQKV = BS * D;
  const long nW = (long)D * D;

  // d_out staging: qb/kb/vb bf16 [0,96M) (dead after proj/vpT GEMMs);
  // red_s partials at +96M; final_emit overwrites all of d_out at the end.
  ushort* qb = (ushort*)d_out;
  ushort* kb = qb + nQKV;
  ushort* vb = kb + nQKV;
  float* red_s_max = (float*)((char*)d_out + (96ull << 20));   // 8*8*2048*4 = 512KB
  float* red_s_sum = (float*)((char*)d_out + (98ull << 20));
  float* Ms        = (float*)((char*)d_out + (100ull << 20));  // 64KB
  float* Zs        = (float*)((char*)d_out + (100ull << 20) + 65536);

  // workspace map:
  //  [0,32M)   qp bf16   -> probs lower       [32,64M) kp bf16 -> probs upper
  //  [64,96M)  vpT bf16 [b][e][s]
  //  [96,160M) Wqb/Wkb/Wvb (early) -> scores bf16 -> attnB bf16 [96,128M)
  //  [128M+)   red_f partials + Mf/Zf
  char* ws = (char*)d_ws;
  ushort* qp     = (ushort*)ws;
  ushort* kp     = (ushort*)(ws + (32ull << 20));
  ushort* vpT    = (ushort*)(ws + (64ull << 20));
  ushort* Wqb    = (ushort*)(ws + (96ull << 20));
  ushort* Wkb    = Wqb + nW;
  ushort* Wvb    = Wkb + nW;
  ushort* scores = (ushort*)(ws + (96ull << 20));
  ushort* probs  = (ushort*)ws;
  ushort* attnB  = (ushort*)(ws + (96ull << 20));
  float* red_f_max = (float*)(ws + (128ull << 20));
  float* red_f_sum = (float*)(ws + (129ull << 20));
  float* Mf        = (float*)(ws + (130ull << 20));
  float* Zf        = (float*)(ws + (131ull << 20));

  const int SH = 131072;  // dynamic LDS bytes for gemm256
  (void)hipFuncSetAttribute(reinterpret_cast<const void*>(&gemm256<1,1,0,0>),
                            hipFuncAttributeMaxDynamicSharedMemorySize, SH);
  (void)hipFuncSetAttribute(reinterpret_cast<const void*>(&gemm256<1,2,0,0>),
                            hipFuncAttributeMaxDynamicSharedMemorySize, SH);
  (void)hipFuncSetAttribute(reinterpret_cast<const void*>(&gemm256<1,0,1,1>),
                            hipFuncAttributeMaxDynamicSharedMemorySize, SH);
  (void)hipFuncSetAttribute(reinterpret_cast<const void*>(&gemm256<1,0,0,1>),
                            hipFuncAttributeMaxDynamicSharedMemorySize, SH);

  auto cvt = [&](const float* src, ushort* dst, long n) {
    int n4 = (int)(n / 4);
    cvt_f32_bf16<<<dim3((n4 + 255) / 256), 256, 0, stream>>>((const float4*)src, (ushort4*)dst, n4);
  };
  cvt(Wq, Wqb, nW);
  cvt(Wk, Wkb, nW);
  cvt(Wv, Wvb, nW);
  cvt(q, qb, nQKV);
  cvt(k, kb, nQKV);
  cvt(v, vb, nQKV);

  // qp[m][e] = q[m][:]·Wq[e][:] + bq[e]   (gm=64, gn=4)
  gemm256<1,1,0,0><<<dim3(64 * 4), 512, SH, stream>>>(
      qb, Wqb, qp, bq, nullptr, nullptr, D, D, 0, 0, 0, 1.f, 64, 4);
  gemm256<1,1,0,0><<<dim3(64 * 4), 512, SH, stream>>>(
      kb, Wkb, kp, bk, nullptr, nullptr, D, D, 0, 0, 0, 1.f, 64, 4);
  // vpT[b][e][s] = Wv[e][:]·v[b][s][:] + bv[e]   (gm=4, gn=8, batch 8)
  gemm256<1,2,0,0><<<dim3(4 * 8 * B), 512, SH, stream>>>(
      Wvb, vb, vpT, bv, nullptr, nullptr, S, D, 0, (long)S * D, (long)D * S, 1.f, 4, 8);
  // scores = qp·kp^T / 1024 + fused softmax pass1   (gm=8, gn=8, batch 8)
  gemm256<1,0,1,1><<<dim3(8 * 8 * B), 512, SH, stream>>>(
      qp, kp, scores, nullptr, red_s_max, red_s_sum,
      S, D, (long)S * D, (long)S * D, (long)S * S, 1.f / 1024.f, 8, 8);

  colsm_combine<<<dim3(S / 256, B), 256, 0, stream>>>(red_s_max, red_s_sum, Ms, Zs, S, 8);
  colsm_emit_bf16<<<dim3(S / 1024, B, 128), 256, 0, stream>>>(scores, probs, Ms, Zs, S, S, 16);

  // attn = probs·vpT^T (bf16) + fused final-softmax pass1   (gm=8, gn=4, batch 8)
  gemm256<1,0,0,1><<<dim3(8 * 4 * B), 512, SH, stream>>>(
      probs, vpT, attnB, nullptr, red_f_max, red_f_sum,
      D, S, (long)S * S, (long)D * S, (long)S * D, 1.f, 8, 4);

  colsm_combine<<<dim3(D / 256, B), 256, 0, stream>>>(red_f_max, red_f_sum, Mf, Zf, D, 8);
  final_emit<<<dim3(1, B, 128), 256, 0, stream>>>(attnB, q, out, out + nQKV, Mf, Zf, S, D, 16);

  (void)in_sizes; (void)n_in; (void)out_size; (void)ws_size;
}

// Round 7
// 428.362 us; speedup vs baseline: 1.3711x; 1.0678x over previous
//
#include <hip/hip_runtime.h>

typedef __attribute__((ext_vector_type(8))) __bf16 bf16x8;
typedef __attribute__((ext_vector_type(4))) float f32x4;

__device__ __forceinline__ ushort f2bf(float f) {
  union { float f; unsigned u; } x; x.f = f;
  unsigned r = x.u + 0x7FFFu + ((x.u >> 16) & 1u);
  return (ushort)(r >> 16);
}
__device__ __forceinline__ float bf2f(ushort u) {
  union { unsigned u; float f; } x; x.u = ((unsigned)u) << 16;
  return x.f;
}

__device__ __forceinline__ void gload_lds16(const void* g, void* l) {
  __builtin_amdgcn_global_load_lds(
      (const __attribute__((address_space(1))) void*)g,
      (__attribute__((address_space(3))) void*)l, 16, 0, 0);
}

// ---------------- fp32 -> bf16 convert ----------------
__global__ __launch_bounds__(256) void cvt_f32_bf16(const float4* __restrict__ in,
                                                    ushort4* __restrict__ out, int n4) {
  int i = blockIdx.x * 256 + threadIdx.x;
  if (i >= n4) return;
  float4 v = in[i];
  ushort4 o;
  o.x = f2bf(v.x); o.y = f2bf(v.y); o.z = f2bf(v.z); o.w = f2bf(v.w);
  out[i] = o;
}

// ================= 256x256 8-wave phase-split bf16 GEMM (B^T form) =================
// C[m,n] = (sum_k A[m,k]*B[n,k]) * (SCALED?scale:1) + bias   (bf16 out)
// 512 threads = 8 waves (2 m x 4 n), per-wave 128x64 output. BK=64, dbuf 128KiB LDS,
// frag-major chunks (1KB = one wave-frag in lane order -> ds_read_b128 conflict-free,
// gload_lds dest linear).
// Phases per K-tile (wait discipline: each phase's vmcnt BEFORE its barrier confirms
// the data the NEXT phase reads; issue order A0,B0 @ph1, B1,A1 @ph2; every retirement
// >=3 phases after issue; never vmcnt(0) in steady loop):
//   ph1: rd A0,B0 | issue A0',B0' | vmcnt(6) [B1 cur ok]  | bar | lgkm0 | 16 MFMA | bar
//   ph2: rd B1    | issue B1',A1' | vmcnt(8) [A1 cur ok]  | bar | lgkm0 | 16 MFMA | bar
//   ph3: rd A1    |               |                        | bar | lgkm0 | 16 MFMA | bar
//   ph4:          |               | vmcnt(4) [A0',B0' ok]  | bar |       | 16 MFMA | bar
// Epilogue: C staged to LDS (bf16 [256][256], 32B-slot XOR swizzle on (row>>2)&3)
// then flushed coalesced (16B/lane full rows). REDUCE: fused col-softmax pass1.
template<int BIAS_MODE, int SCALED, int REDUCE>
__global__ __launch_bounds__(512, 2) void gemm256(
    const ushort* __restrict__ A, const ushort* __restrict__ B,
    ushort* __restrict__ Cv, const float* __restrict__ bias,
    float* __restrict__ red_max, float* __restrict__ red_sum,
    int N, int K, long sA, long sB, long sC, float scale, int gm, int gn)
{
  extern __shared__ ushort lds[];   // 131072 B

  // ---- tile decode: bijective XCD swizzle + banded order ----
  const int nwg = gridDim.x;
  const int wg = blockIdx.x;
  const int cpx = nwg >> 3;
  const int wid_ = (wg & 7) * cpx + (wg >> 3);
  const int tiles = gm * gn;
  const int bz = wid_ / tiles;
  const int t2 = wid_ - bz * tiles;
  const int band = t2 / (gm << 2);
  const int r2 = t2 - band * (gm << 2);
  const int tile_m = (r2 >> 2) * 256;
  const int tile_n = ((band << 2) + (r2 & 3)) * 256;

  const ushort* Ab = A + (size_t)bz * sA;
  const ushort* Bb = B + (size_t)bz * sB;
  const int t = threadIdx.x;
  const int lane = t & 63;
  const int w = t >> 6;
  const int wr = w >> 2;
  const int wc = w & 3;

  f32x4 acc[8][4] = {};
  bf16x8 aA[4][2], bB[4][2];

#define LDA(c, q)                                                                     \
  _Pragma("unroll") for (int mi = 0; mi < 4; ++mi)                                    \
  _Pragma("unroll") for (int kk = 0; kk < 2; ++kk)                                    \
    aA[mi][kk] = *(const bf16x8*)&lds[(c) * 16384 +                                   \
        ((wr * 8 + (q) * 4 + mi) * 2 + kk) * 512 + lane * 8];

#define LDB(c, h)                                                                     \
  _Pragma("unroll") for (int nf = 0; nf < 2; ++nf)                                    \
  _Pragma("unroll") for (int kk = 0; kk < 2; ++kk)                                    \
    bB[(h) * 2 + nf][kk] = *(const bf16x8*)&lds[32768 + (c) * 16384 +                 \
        ((wc * 4 + (h) * 2 + nf) * 2 + kk) * 512 + lane * 8];

#define STAGE_A(c, k0, q)                                                             \
  _Pragma("unroll") for (int o = 0; o < 2; ++o) {                                     \
    int g = w * 2 + o;                                                                \
    int rowblk = (g >> 3) * 8 + (q) * 4 + ((g >> 1) & 3);                             \
    int kk = g & 1;                                                                   \
    gload_lds16(Ab + (size_t)(tile_m + rowblk * 16 + (lane & 15)) * K +               \
                    (k0) + kk * 32 + (lane >> 4) * 8,                                 \
                &lds[(c) * 16384 + (rowblk * 2 + kk) * 512]);                         \
  }

#define STAGE_B(c, k0, q)                                                             \
  _Pragma("unroll") for (int o = 0; o < 2; ++o) {                                     \
    int g = w * 2 + o;                                                                \
    int rowblk = (g >> 2) * 4 + (q) * 2 + ((g >> 1) & 1);                             \
    int kk = g & 1;                                                                   \
    gload_lds16(Bb + (size_t)(tile_n + rowblk * 16 + (lane & 15)) * K +               \
                    (k0) + kk * 32 + (lane >> 4) * 8,                                 \
                &lds[32768 + (c) * 16384 + (rowblk * 2 + kk) * 512]);                 \
  }

#define MFMA_PH(MB, NB)                                                               \
  _Pragma("unroll") for (int kk = 0; kk < 2; ++kk)                                    \
  _Pragma("unroll") for (int mi = 0; mi < 4; ++mi)                                    \
  _Pragma("unroll") for (int nf = 0; nf < 2; ++nf)                                    \
    acc[(MB) + mi][(NB) + nf] = __builtin_amdgcn_mfma_f32_16x16x32_bf16(              \
        aA[mi][kk], bB[(NB) + nf][kk], acc[(MB) + mi][(NB) + nf], 0, 0, 0);

#define ITER(c, DOSTAGE, k0n, W1, W2, W4)                                             \
  {                                                                                   \
    /* ---- phase 1: m0-3 x n0-1 ---- */                                              \
    LDA(c, 0);                                                                        \
    LDB(c, 0);                                                                        \
    if (DOSTAGE) { STAGE_A((c) ^ 1, k0n, 0); STAGE_B((c) ^ 1, k0n, 0); }              \
    asm volatile(W1 ::: "memory");                                                    \
    __builtin_amdgcn_s_barrier();                                                     \
    asm volatile("s_waitcnt lgkmcnt(0)" ::: "memory");                                \
    __builtin_amdgcn_sched_barrier(0);                                                \
    __builtin_amdgcn_s_setprio(1);                                                    \
    MFMA_PH(0, 0);                                                                    \
    __builtin_amdgcn_s_setprio(0);                                                    \
    __builtin_amdgcn_s_barrier();                                                     \
    /* ---- phase 2: m0-3 x n2-3 ---- */                                              \
    LDB(c, 1);                                                                        \
    if (DOSTAGE) { STAGE_B((c) ^ 1, k0n, 1); STAGE_A((c) ^ 1, k0n, 1); }              \
    asm volatile(W2 ::: "memory");                                                    \
    __builtin_amdgcn_s_barrier();                                                     \
    asm volatile("s_waitcnt lgkmcnt(0)" ::: "memory");                                \
    __builtin_amdgcn_sched_barrier(0);                                                \
    __builtin_amdgcn_s_setprio(1);                                                    \
    MFMA_PH(0, 2);                                                                    \
    __builtin_amdgcn_s_setprio(0);                                                    \
    __builtin_amdgcn_s_barrier();                                                     \
    /* ---- phase 3: m4-7 x n0-1 ---- */                                              \
    LDA(c, 1);                                                                        \
    __builtin_amdgcn_s_barrier();                                                     \
    asm volatile("s_waitcnt lgkmcnt(0)" ::: "memory");                                \
    __builtin_amdgcn_sched_barrier(0);                                                \
    __builtin_amdgcn_s_setprio(1);                                                    \
    MFMA_PH(4, 0);                                                                    \
    __builtin_amdgcn_s_setprio(0);                                                    \
    __builtin_amdgcn_s_barrier();                                                     \
    /* ---- phase 4: m4-7 x n2-3 ---- */                                              \
    asm volatile(W4 ::: "memory");                                                    \
    __builtin_amdgcn_s_barrier();                                                     \
    __builtin_amdgcn_sched_barrier(0);                                                \
    __builtin_amdgcn_s_setprio(1);                                                    \
    MFMA_PH(4, 2);                                                                    \
    __builtin_amdgcn_s_setprio(0);                                                    \
    __builtin_amdgcn_s_barrier();                                                     \
  }

  // ---- prologue: stage K-tile 0 into buf 0 (issue order A0,B0,B1,A1) ----
  STAGE_A(0, 0, 0);
  STAGE_B(0, 0, 0);
  STAGE_B(0, 0, 1);
  STAGE_A(0, 0, 1);
  asm volatile("s_waitcnt vmcnt(4)" ::: "memory");  // A0,B0 landed; B1,A1 in flight
  __builtin_amdgcn_s_barrier();

  const int KT = K >> 6;
  for (int tt = 0; tt < KT - 1; ++tt) {
    const int c = tt & 1;
    const int k0n = (tt + 1) << 6;
    ITER(c, true, k0n,
         "s_waitcnt vmcnt(6)", "s_waitcnt vmcnt(8)", "s_waitcnt vmcnt(4)");
  }
  // peeled last K-tile: entry outstanding = [B1 cur, A1 cur] = 4 ops
  ITER(((KT - 1) & 1), false, 0,
       "s_waitcnt vmcnt(2)", "s_waitcnt vmcnt(0)", "s_nop 0");

#undef ITER
#undef MFMA_PH
#undef STAGE_A
#undef STAGE_B
#undef LDA
#undef LDB

  // ---- epilogue: stage C tile into LDS (bf16, XOR-swizzled 32B slots) ----
  {
    float bcn[4]; int ccl[4];
#pragma unroll
    for (int nf = 0; nf < 4; ++nf) {
      ccl[nf] = wc * 64 + nf * 16 + (lane & 15);
      bcn[nf] = (BIAS_MODE == 1) ? bias[tile_n + ccl[nf]] : 0.f;
    }
    const int g5 = ((lane >> 4) & 3) << 5;
#pragma unroll
    for (int mi = 0; mi < 8; ++mi) {
#pragma unroll
      for (int j = 0; j < 4; ++j) {
        const int row = wr * 128 + mi * 16 + ((lane >> 4) << 2) + j;
        float bcr = (BIAS_MODE == 2) ? bias[tile_m + row] : 0.f;
#pragma unroll
        for (int nf = 0; nf < 4; ++nf) {
          float val = acc[mi][nf][j];
          if (SCALED) val *= scale;
          if (BIAS_MODE == 1) val += bcn[nf];
          else if (BIAS_MODE == 2) val += bcr;
          *(ushort*)((char*)lds + row * 512 + ((ccl[nf] * 2) ^ g5)) = f2bf(val);
        }
      }
    }
  }
  __syncthreads();
  // ---- coalesced flush: 16 passes x 512 threads x 16B ----
#pragma unroll
  for (int p = 0; p < 16; ++p) {
    int off = p * 8192 + t * 16;
    int row = off >> 9;
    int b = off & 511;
    int bs = b ^ (((row >> 2) & 3) << 5);
    float4 d = *(const float4*)((const char*)lds + row * 512 + bs);
    *(float4*)(Cv + (size_t)bz * sC + (size_t)(tile_m + row) * N + tile_n + (b >> 1)) = d;
  }

  // ---- fused column-softmax pass1 (recompute from acc) ----
  if constexpr (REDUCE) {
    __syncthreads();   // flush LDS reads done; reuse lds[0..4KB)
    float* mb = (float*)lds;          // [2][256]
    float* sb = (float*)lds + 512;    // [2][256]
#pragma unroll
    for (int nf = 0; nf < 4; ++nf) {
      const int cl = wc * 64 + nf * 16 + (lane & 15);
      const float bcn_ = (BIAS_MODE == 1) ? bias[tile_n + cl] : 0.f;
      float mx = -1e30f;
#pragma unroll
      for (int mi = 0; mi < 8; ++mi)
#pragma unroll
        for (int j = 0; j < 4; ++j) {
          float val = acc[mi][nf][j];
          if (SCALED) val *= scale;
          if (BIAS_MODE == 1) val += bcn_;
          mx = fmaxf(mx, val);
        }
      float m1 = fmaxf(mx, __shfl_xor(mx, 16));
      float M = fmaxf(m1, __shfl_xor(m1, 32));
      float sm = 0.f;
#pragma unroll
      for (int mi = 0; mi < 8; ++mi)
#pragma unroll
        for (int j = 0; j < 4; ++j) {
          float val = acc[mi][nf][j];
          if (SCALED) val *= scale;
          if (BIAS_MODE == 1) val += bcn_;
          sm += __expf(val - M);
        }
      float s1 = sm + __shfl_xor(sm, 16);
      float Ss = s1 + __shfl_xor(s1, 32);
      if ((lane >> 4) == nf) {
        mb[wr * 256 + cl] = M;
        sb[wr * 256 + cl] = Ss;
      }
    }
    __syncthreads();
    if (t < 256) {
      float m0 = mb[t], m1v = mb[256 + t];
      float M = fmaxf(m0, m1v);
      float Ss = sb[t] * __expf(m0 - M) + sb[256 + t] * __expf(m1v - M);
      size_t rb = ((size_t)bz * gm + (tile_m >> 8)) * N + tile_n + t;
      red_max[rb] = M;
      red_sum[rb] = Ss;
    }
  }
}

// combine partials -> M, 1/Z per (b,col). grid: (cols/256, B)
__global__ __launch_bounds__(256) void colsm_combine(
    const float* __restrict__ red_max, const float* __restrict__ red_sum,
    float* __restrict__ Mv, float* __restrict__ Zinv, int cols, int nch)
{
  const int b = blockIdx.y;
  const int c = blockIdx.x * 256 + threadIdx.x;
  float M = -1e30f, Z = 0.f;
  for (int ch = 0; ch < nch; ++ch) {
    size_t o = ((size_t)b * nch + ch) * cols + c;
    float m = red_max[o], s = red_sum[o];
    float nm = fmaxf(M, m);
    Z = Z * __expf(M - nm) + s * __expf(m - nm);
    M = nm;
  }
  Mv[(size_t)b * cols + c] = M;
  Zinv[(size_t)b * cols + c] = 1.f / Z;
}

// emit bf16 probs = exp(scores - M[col]) * Zinv[col]
__global__ __launch_bounds__(256) void colsm_emit_bf16(
    const ushort* __restrict__ X, ushort* __restrict__ P,
    const float* __restrict__ Mv, const float* __restrict__ Zinv,
    int rows, int cols, int rpc)
{
  const int b = blockIdx.y;
  const int ch = blockIdx.z;
  const size_t base = (size_t)b * rows * cols;
  const int c4 = (blockIdx.x * 256 + threadIdx.x) * 4;
  const int r0 = ch * rpc;
  float M[4], Zi[4];
#pragma unroll
  for (int i = 0; i < 4; ++i) {
    M[i] = Mv[(size_t)b * cols + c4 + i];
    Zi[i] = Zinv[(size_t)b * cols + c4 + i];
  }
  for (int r = r0; r < r0 + rpc; ++r) {
    size_t o = base + (size_t)r * cols + c4;
    ushort4 u = *(const ushort4*)(X + o);
    ushort4 wv;
    wv.x = f2bf(__expf(bf2f(u.x) - M[0]) * Zi[0]);
    wv.y = f2bf(__expf(bf2f(u.y) - M[1]) * Zi[1]);
    wv.z = f2bf(__expf(bf2f(u.z) - M[2]) * Zi[2]);
    wv.w = f2bf(__expf(bf2f(u.w) - M[3]) * Zi[3]);
    *(ushort4*)(P + o) = wv;
  }
}

// final: out1 = softmax(attn over rows), out0 = attn + residual. attn is bf16.
__global__ __launch_bounds__(256) void final_emit(
    const ushort* __restrict__ attnB, const float* __restrict__ q,
    float* __restrict__ out0, float* __restrict__ out1,
    const float* __restrict__ Mv, const float* __restrict__ Zinv,
    int rows, int cols, int rpc)
{
  const int b = blockIdx.y;
  const int ch = blockIdx.z;
  const size_t base = (size_t)b * rows * cols;
  const int c4 = (blockIdx.x * 256 + threadIdx.x) * 4;
  const int r0 = ch * rpc;
  float M[4], Zi[4];
#pragma unroll
  for (int i = 0; i < 4; ++i) {
    M[i] = Mv[(size_t)b * cols + c4 + i];
    Zi[i] = Zinv[(size_t)b * cols + c4 + i];
  }
  for (int r = r0; r < r0 + rpc; ++r) {
    size_t o = base + (size_t)r * cols + c4;
    ushort4 u = *(const ushort4*)(attnB + o);
    float4 qv = *(const float4*)(q + o);
    float a0 = bf2f(u.x), a1 = bf2f(u.y), a2 = bf2f(u.z), a3 = bf2f(u.w);
    float4 wv, s;
    wv.x = __expf(a0 - M[0]) * Zi[0];
    wv.y = __expf(a1 - M[1]) * Zi[1];
    wv.z = __expf(a2 - M[2]) * Zi[2];
    wv.w = __expf(a3 - M[3]) * Zi[3];
    s.x = a0 + qv.x; s.y = a1 + qv.y; s.z = a2 + qv.z; s.w = a3 + qv.w;
    *(float4*)(out1 + o) = wv;
    *(float4*)(out0 + o) = s;
  }
}

extern "C" void kernel_launch(void* const* d_in, const int* in_sizes, int n_in,
                              void* d_out, int out_size, void* d_ws, size_t ws_size,
                              hipStream_t stream) {
  const float* q  = (const float*)d_in[0];
  const float* k  = (const float*)d_in[1];
  const float* v  = (const float*)d_in[2];
  const float* Wq = (const float*)d_in[3];
  const float* bq = (const float*)d_in[4];
  const float* Wk = (const float*)d_in[5];
  const float* bk = (const float*)d_in[6];
  const float* Wv = (const float*)d_in[7];
  const float* bv = (const float*)d_in[8];
  float* out = (float*)d_out;

  const int B = 8, S = 2048, D = 1024;
  const long BS = (long)B * S;
  const long nQKV = BS * D;
  const long nW = (long)D * D;

  // d_out staging: qb/kb/vb bf16 [0,96M); red_s partials at +96M;
  // final_emit overwrites all of d_out at the end.
  ushort* qb = (ushort*)d_out;
  ushort* kb = qb + nQKV;
  ushort* vb = kb + nQKV;
  float* red_s_max = (float*)((char*)d_out + (96ull << 20));
  float* red_s_sum = (float*)((char*)d_out + (98ull << 20));
  float* Ms        = (float*)((char*)d_out + (100ull << 20));
  float* Zs        = (float*)((char*)d_out + (100ull << 20) + 65536);

  // workspace map:
  //  [0,32M) qp -> probs lower  [32,64M) kp -> probs upper  [64,96M) vpT
  //  [96,160M) Wqb/Wkb/Wvb (early) -> scores -> attnB [96,128M)
  //  [128M+) red_f + Mf/Zf
  char* ws = (char*)d_ws;
  ushort* qp     = (ushort*)ws;
  ushort* kp     = (ushort*)(ws + (32ull << 20));
  ushort* vpT    = (ushort*)(ws + (64ull << 20));
  ushort* Wqb    = (ushort*)(ws + (96ull << 20));
  ushort* Wkb    = Wqb + nW;
  ushort* Wvb    = Wkb + nW;
  ushort* scores = (ushort*)(ws + (96ull << 20));
  ushort* probs  = (ushort*)ws;
  ushort* attnB  = (ushort*)(ws + (96ull << 20));
  float* red_f_max = (float*)(ws + (128ull << 20));
  float* red_f_sum = (float*)(ws + (129ull << 20));
  float* Mf        = (float*)(ws + (130ull << 20));
  float* Zf        = (float*)(ws + (131ull << 20));

  const int SH = 131072;
  (void)hipFuncSetAttribute(reinterpret_cast<const void*>(&gemm256<1,0,0>),
                            hipFuncAttributeMaxDynamicSharedMemorySize, SH);
  (void)hipFuncSetAttribute(reinterpret_cast<const void*>(&gemm256<2,0,0>),
                            hipFuncAttributeMaxDynamicSharedMemorySize, SH);
  (void)hipFuncSetAttribute(reinterpret_cast<const void*>(&gemm256<0,1,1>),
                            hipFuncAttributeMaxDynamicSharedMemorySize, SH);
  (void)hipFuncSetAttribute(reinterpret_cast<const void*>(&gemm256<0,0,1>),
                            hipFuncAttributeMaxDynamicSharedMemorySize, SH);

  auto cvt = [&](const float* src, ushort* dst, long n) {
    int n4 = (int)(n / 4);
    cvt_f32_bf16<<<dim3((n4 + 255) / 256), 256, 0, stream>>>((const float4*)src, (ushort4*)dst, n4);
  };
  cvt(Wq, Wqb, nW);
  cvt(Wk, Wkb, nW);
  cvt(Wv, Wvb, nW);
  cvt(q, qb, nQKV);
  cvt(k, kb, nQKV);
  cvt(v, vb, nQKV);

  // qp[m][e] = q[m][:]·Wq[e][:] + bq[e]   (gm=64, gn=4)
  gemm256<1,0,0><<<dim3(64 * 4), 512, SH, stream>>>(
      qb, Wqb, qp, bq, nullptr, nullptr, D, D, 0, 0, 0, 1.f, 64, 4);
  gemm256<1,0,0><<<dim3(64 * 4), 512, SH, stream>>>(
      kb, Wkb, kp, bk, nullptr, nullptr, D, D, 0, 0, 0, 1.f, 64, 4);
  // vpT[b][e][s] = Wv[e][:]·v[b][s][:] + bv[e]   (gm=4, gn=8, batch 8)
  gemm256<2,0,0><<<dim3(4 * 8 * B), 512, SH, stream>>>(
      Wvb, vb, vpT, bv, nullptr, nullptr, S, D, 0, (long)S * D, (long)D * S, 1.f, 4, 8);
  // scores = qp·kp^T / 1024 + fused softmax pass1   (gm=8, gn=8, batch 8)
  gemm256<0,1,1><<<dim3(8 * 8 * B), 512, SH, stream>>>(
      qp, kp, scores, nullptr, red_s_max, red_s_sum,
      S, D, (long)S * D, (long)S * D, (long)S * S, 1.f / 1024.f, 8, 8);

  colsm_combine<<<dim3(S / 256, B), 256, 0, stream>>>(red_s_max, red_s_sum, Ms, Zs, S, 8);
  colsm_emit_bf16<<<dim3(S / 1024, B, 128), 256, 0, stream>>>(scores, probs, Ms, Zs, S, S, 16);

  // attn = probs·vpT^T (bf16) + fused final-softmax pass1   (gm=8, gn=4, batch 8)
  gemm256<0,0,1><<<dim3(8 * 4 * B), 512, SH, stream>>>(
      probs, vpT, attnB, nullptr, red_f_max, red_f_sum,
      D, S, (long)S * S, (long)D * S, (long)S * D, 1.f, 8, 4);

  colsm_combine<<<dim3(D / 256, B), 256, 0, stream>>>(red_f_max, red_f_sum, Mf, Zf, D, 8);
  final_emit<<<dim3(1, B, 128), 256, 0, stream>>>(attnB, q, out, out + nQKV, Mf, Zf, S, D, 16);

  (void)in_sizes; (void)n_in; (void)out_size; (void)ws_size;
}

// Round 8
// 424.329 us; speedup vs baseline: 1.3841x; 1.0095x over previous
//
#include <hip/hip_runtime.h>

typedef __attribute__((ext_vector_type(8))) __bf16 bf16x8;
typedef __attribute__((ext_vector_type(4))) float f32x4;

__device__ __forceinline__ ushort f2bf(float f) {
  union { float f; unsigned u; } x; x.f = f;
  unsigned r = x.u + 0x7FFFu + ((x.u >> 16) & 1u);
  return (ushort)(r >> 16);
}
__device__ __forceinline__ float bf2f(ushort u) {
  union { unsigned u; float f; } x; x.u = ((unsigned)u) << 16;
  return x.f;
}

__device__ __forceinline__ void gload_lds16(const void* g, void* l) {
  __builtin_amdgcn_global_load_lds(
      (const __attribute__((address_space(1))) void*)g,
      (__attribute__((address_space(3))) void*)l, 16, 0, 0);
}

// ---------------- fp32 -> bf16 convert ----------------
__global__ __launch_bounds__(256) void cvt_f32_bf16(const float4* __restrict__ in,
                                                    ushort4* __restrict__ out, int n4) {
  int i = blockIdx.x * 256 + threadIdx.x;
  if (i >= n4) return;
  float4 v = in[i];
  ushort4 o;
  o.x = f2bf(v.x); o.y = f2bf(v.y); o.z = f2bf(v.z); o.w = f2bf(v.w);
  out[i] = o;
}

// ================= 256x256 8-wave phase-split bf16 GEMM (B^T form) =================
// C[m,n] = f( (sum_k A[m,k]*B[n,k]) * (SCALED?scale:1) + bias ),  f = exp if EXPOUT
// 512 threads = 8 waves (2m x 4n), per-wave 128x64. BK=64, dbuf 128KiB LDS,
// frag-major chunks (1KB = one wave-frag in lane order; conflict-free ds_read_b128,
// linear gload_lds dest).
// 2 waits per K-tile, all issue->wait distances >= 3 phases, never vmcnt(0) steady:
//   ph1: rd A0,B0 | issue A0',B0' | W1 vmcnt(4) [retires B1,A1 cur] | bar|lgkm0|16 MFMA|bar
//   ph2: rd B1    | issue B1',A1' |                                  bar|lgkm0|16 MFMA|bar
//   ph3: rd A1    |               |                                  bar|lgkm0|16 MFMA|bar
//   ph4:          |               | W4 vmcnt(4) [retires A0',B0']  | bar|      16 MFMA|bar
// Epilogue: C staged to LDS (bf16, 32B-slot XOR swizzle), coalesced flush.
// REDUCE: 0 none; 1 col max+sumexp partials; 2 col plain-sum partials (EXPOUT path).
template<int BIAS_MODE, int SCALED, int REDUCE, int EXPOUT>
__global__ __launch_bounds__(512, 2) void gemm256(
    const ushort* __restrict__ A, const ushort* __restrict__ B,
    ushort* __restrict__ Cv, const float* __restrict__ bias,
    float* __restrict__ red_max, float* __restrict__ red_sum,
    int N, int K, long sA, long sB, long sC, float scale, int gm, int gn)
{
  extern __shared__ ushort lds[];   // 131072 B

  // ---- tile decode: bijective XCD swizzle + banded order ----
  const int nwg = gridDim.x;
  const int wg = blockIdx.x;
  const int cpx = nwg >> 3;
  const int wid_ = (wg & 7) * cpx + (wg >> 3);
  const int tiles = gm * gn;
  const int bz = wid_ / tiles;
  const int t2 = wid_ - bz * tiles;
  const int band = t2 / (gm << 2);
  const int r2 = t2 - band * (gm << 2);
  const int tile_m = (r2 >> 2) * 256;
  const int tile_n = ((band << 2) + (r2 & 3)) * 256;

  const ushort* Ab = A + (size_t)bz * sA;
  const ushort* Bb = B + (size_t)bz * sB;
  const int t = threadIdx.x;
  const int lane = t & 63;
  const int w = t >> 6;
  const int wr = w >> 2;
  const int wc = w & 3;

  f32x4 acc[8][4] = {};
  bf16x8 aA[4][2], bB[4][2];

#define LDA(c, q)                                                                     \
  _Pragma("unroll") for (int mi = 0; mi < 4; ++mi)                                    \
  _Pragma("unroll") for (int kk = 0; kk < 2; ++kk)                                    \
    aA[mi][kk] = *(const bf16x8*)&lds[(c) * 16384 +                                   \
        ((wr * 8 + (q) * 4 + mi) * 2 + kk) * 512 + lane * 8];

#define LDB(c, h)                                                                     \
  _Pragma("unroll") for (int nf = 0; nf < 2; ++nf)                                    \
  _Pragma("unroll") for (int kk = 0; kk < 2; ++kk)                                    \
    bB[(h) * 2 + nf][kk] = *(const bf16x8*)&lds[32768 + (c) * 16384 +                 \
        ((wc * 4 + (h) * 2 + nf) * 2 + kk) * 512 + lane * 8];

#define STAGE_A(c, k0, q)                                                             \
  _Pragma("unroll") for (int o = 0; o < 2; ++o) {                                     \
    int g = w * 2 + o;                                                                \
    int rowblk = (g >> 3) * 8 + (q) * 4 + ((g >> 1) & 3);                             \
    int kk = g & 1;                                                                   \
    gload_lds16(Ab + (size_t)(tile_m + rowblk * 16 + (lane & 15)) * K +               \
                    (k0) + kk * 32 + (lane >> 4) * 8,                                 \
                &lds[(c) * 16384 + (rowblk * 2 + kk) * 512]);                         \
  }

#define STAGE_B(c, k0, q)                                                             \
  _Pragma("unroll") for (int o = 0; o < 2; ++o) {                                     \
    int g = w * 2 + o;                                                                \
    int rowblk = (g >> 2) * 4 + (q) * 2 + ((g >> 1) & 1);                             \
    int kk = g & 1;                                                                   \
    gload_lds16(Bb + (size_t)(tile_n + rowblk * 16 + (lane & 15)) * K +               \
                    (k0) + kk * 32 + (lane >> 4) * 8,                                 \
                &lds[32768 + (c) * 16384 + (rowblk * 2 + kk) * 512]);                 \
  }

#define MFMA_PH(MB, NB)                                                               \
  _Pragma("unroll") for (int kk = 0; kk < 2; ++kk)                                    \
  _Pragma("unroll") for (int mi = 0; mi < 4; ++mi)                                    \
  _Pragma("unroll") for (int nf = 0; nf < 2; ++nf)                                    \
    acc[(MB) + mi][(NB) + nf] = __builtin_amdgcn_mfma_f32_16x16x32_bf16(              \
        aA[mi][kk], bB[(NB) + nf][kk], acc[(MB) + mi][(NB) + nf], 0, 0, 0);

#define ITER(c, DOSTAGE, k0n, W1, W4)                                                 \
  {                                                                                   \
    /* ---- phase 1: m0-3 x n0-1 ---- */                                              \
    LDA(c, 0);                                                                        \
    LDB(c, 0);                                                                        \
    if (DOSTAGE) { STAGE_A((c) ^ 1, k0n, 0); STAGE_B((c) ^ 1, k0n, 0); }              \
    asm volatile(W1 ::: "memory");                                                    \
    __builtin_amdgcn_s_barrier();                                                     \
    asm volatile("s_waitcnt lgkmcnt(0)" ::: "memory");                                \
    __builtin_amdgcn_sched_barrier(0);                                                \
    __builtin_amdgcn_s_setprio(1);                                                    \
    MFMA_PH(0, 0);                                                                    \
    __builtin_amdgcn_s_setprio(0);                                                    \
    __builtin_amdgcn_s_barrier();                                                     \
    /* ---- phase 2: m0-3 x n2-3 ---- */                                              \
    LDB(c, 1);                                                                        \
    if (DOSTAGE) { STAGE_B((c) ^ 1, k0n, 1); STAGE_A((c) ^ 1, k0n, 1); }              \
    __builtin_amdgcn_s_barrier();                                                     \
    asm volatile("s_waitcnt lgkmcnt(0)" ::: "memory");                                \
    __builtin_amdgcn_sched_barrier(0);                                                \
    __builtin_amdgcn_s_setprio(1);                                                    \
    MFMA_PH(0, 2);                                                                    \
    __builtin_amdgcn_s_setprio(0);                                                    \
    __builtin_amdgcn_s_barrier();                                                     \
    /* ---- phase 3: m4-7 x n0-1 ---- */                                              \
    LDA(c, 1);                                                                        \
    __builtin_amdgcn_s_barrier();                                                     \
    asm volatile("s_waitcnt lgkmcnt(0)" ::: "memory");                                \
    __builtin_amdgcn_sched_barrier(0);                                                \
    __builtin_amdgcn_s_setprio(1);                                                    \
    MFMA_PH(4, 0);                                                                    \
    __builtin_amdgcn_s_setprio(0);                                                    \
    __builtin_amdgcn_s_barrier();                                                     \
    /* ---- phase 4: m4-7 x n2-3 ---- */                                              \
    asm volatile(W4 ::: "memory");                                                    \
    __builtin_amdgcn_s_barrier();                                                     \
    __builtin_amdgcn_sched_barrier(0);                                                \
    __builtin_amdgcn_s_setprio(1);                                                    \
    MFMA_PH(4, 2);                                                                    \
    __builtin_amdgcn_s_setprio(0);                                                    \
    __builtin_amdgcn_s_barrier();                                                     \
  }

  // ---- prologue: stage K-tile 0 into buf 0, issue order A0,B0,B1,A1 ----
  STAGE_A(0, 0, 0);
  STAGE_B(0, 0, 0);
  STAGE_B(0, 0, 1);
  STAGE_A(0, 0, 1);
  asm volatile("s_waitcnt vmcnt(4)" ::: "memory");  // A0,B0 landed; B1,A1 in flight
  __builtin_amdgcn_s_barrier();

  const int KT = K >> 6;
  for (int tt = 0; tt < KT - 1; ++tt) {
    const int c = tt & 1;
    const int k0n = (tt + 1) << 6;
    ITER(c, true, k0n, "s_waitcnt vmcnt(4)", "s_waitcnt vmcnt(4)");
  }
  // peeled last K-tile: entry outstanding = [B1 cur, A1 cur] = 4 ops
  ITER(((KT - 1) & 1), false, 0, "s_waitcnt vmcnt(0)", "s_nop 0");

#undef ITER
#undef MFMA_PH
#undef STAGE_A
#undef STAGE_B
#undef LDA
#undef LDB

  // ---- epilogue: stage C tile into LDS (bf16, XOR-swizzled 32B slots) ----
  float sm2[4] = {0.f, 0.f, 0.f, 0.f};   // REDUCE==2 column sums
  {
    float bcn[4]; int ccl[4];
#pragma unroll
    for (int nf = 0; nf < 4; ++nf) {
      ccl[nf] = wc * 64 + nf * 16 + (lane & 15);
      bcn[nf] = (BIAS_MODE == 1) ? bias[tile_n + ccl[nf]] : 0.f;
    }
    const int g5 = ((lane >> 4) & 3) << 5;
#pragma unroll
    for (int mi = 0; mi < 8; ++mi) {
#pragma unroll
      for (int j = 0; j < 4; ++j) {
        const int row = wr * 128 + mi * 16 + ((lane >> 4) << 2) + j;
        float bcr = (BIAS_MODE == 2) ? bias[tile_m + row] : 0.f;
#pragma unroll
        for (int nf = 0; nf < 4; ++nf) {
          float val = acc[mi][nf][j];
          if (SCALED) val *= scale;
          if (BIAS_MODE == 1) val += bcn[nf];
          else if (BIAS_MODE == 2) val += bcr;
          if (EXPOUT) val = __expf(val);
          if (REDUCE == 2) sm2[nf] += val;
          *(ushort*)((char*)lds + row * 512 + ((ccl[nf] * 2) ^ g5)) = f2bf(val);
        }
      }
    }
  }
  __syncthreads();
  // ---- coalesced flush: 16 passes x 512 threads x 16B ----
#pragma unroll
  for (int p = 0; p < 16; ++p) {
    int off = p * 8192 + t * 16;
    int row = off >> 9;
    int b = off & 511;
    int bs = b ^ (((row >> 2) & 3) << 5);
    float4 d = *(const float4*)((const char*)lds + row * 512 + bs);
    *(float4*)(Cv + (size_t)bz * sC + (size_t)(tile_m + row) * N + tile_n + (b >> 1)) = d;
  }

  if constexpr (REDUCE == 2) {   // plain column-sum partials (expS path)
    __syncthreads();
    float* sb = (float*)lds;     // [2][256]
#pragma unroll
    for (int nf = 0; nf < 4; ++nf) {
      float s1 = sm2[nf] + __shfl_xor(sm2[nf], 16);
      float Ss = s1 + __shfl_xor(s1, 32);
      if ((lane >> 4) == nf)
        sb[wr * 256 + wc * 64 + nf * 16 + (lane & 15)] = Ss;
    }
    __syncthreads();
    if (t < 256) {
      size_t rb = ((size_t)bz * gm + (tile_m >> 8)) * N + tile_n + t;
      red_sum[rb] = sb[t] + sb[256 + t];
    }
  }
  if constexpr (REDUCE == 1) {   // col max+sumexp partials (recompute from acc)
    __syncthreads();
    float* mb = (float*)lds;          // [2][256]
    float* sb = (float*)lds + 512;    // [2][256]
#pragma unroll
    for (int nf = 0; nf < 4; ++nf) {
      const int cl = wc * 64 + nf * 16 + (lane & 15);
      const float bcn_ = (BIAS_MODE == 1) ? bias[tile_n + cl] : 0.f;
      float mx = -1e30f;
#pragma unroll
      for (int mi = 0; mi < 8; ++mi)
#pragma unroll
        for (int j = 0; j < 4; ++j) {
          float val = acc[mi][nf][j];
          if (SCALED) val *= scale;
          if (BIAS_MODE == 1) val += bcn_;
          mx = fmaxf(mx, val);
        }
      float m1 = fmaxf(mx, __shfl_xor(mx, 16));
      float M = fmaxf(m1, __shfl_xor(m1, 32));
      float sm = 0.f;
#pragma unroll
      for (int mi = 0; mi < 8; ++mi)
#pragma unroll
        for (int j = 0; j < 4; ++j) {
          float val = acc[mi][nf][j];
          if (SCALED) val *= scale;
          if (BIAS_MODE == 1) val += bcn_;
          sm += __expf(val - M);
        }
      float s1 = sm + __shfl_xor(sm, 16);
      float Ss = s1 + __shfl_xor(s1, 32);
      if ((lane >> 4) == nf) {
        mb[wr * 256 + cl] = M;
        sb[wr * 256 + cl] = Ss;
      }
    }
    __syncthreads();
    if (t < 256) {
      float m0 = mb[t], m1v = mb[256 + t];
      float M = fmaxf(m0, m1v);
      float Ss = sb[t] * __expf(m0 - M) + sb[256 + t] * __expf(m1v - M);
      size_t rb = ((size_t)bz * gm + (tile_m >> 8)) * N + tile_n + t;
      red_max[rb] = M;
      red_sum[rb] = Ss;
    }
  }
}

// c[b,k] = 1 / sum_ch red_sum[b][ch][k]. grid: (cols/256, B)
__global__ __launch_bounds__(256) void combine_c(
    const float* __restrict__ red_sum, float* __restrict__ cvec, int cols, int nch)
{
  const int b = blockIdx.y;
  const int c = blockIdx.x * 256 + threadIdx.x;
  float Z = 0.f;
  for (int ch = 0; ch < nch; ++ch)
    Z += red_sum[((size_t)b * nch + ch) * cols + c];
  cvec[(size_t)b * cols + c] = 1.f / Z;
}

// vs[b][d][k] = vpT[b][d][k] * c[b][k]   (bf16, 8 elems/thread)
__global__ __launch_bounds__(256) void scale_v(
    const ushort* __restrict__ vpT, const float* __restrict__ cvec,
    ushort* __restrict__ vs, int S, int DS)   // DS = D*S
{
  const size_t k8 = ((size_t)blockIdx.x * 256 + threadIdx.x) * 8;
  const int b = (int)(k8 / DS);
  const int kcol = (int)(k8 % S);
  ushort4 u0 = *(const ushort4*)(vpT + k8);
  ushort4 u1 = *(const ushort4*)(vpT + k8 + 4);
  const float* cb = cvec + (size_t)b * S + kcol;
  float4 c0 = *(const float4*)cb;
  float4 c1 = *(const float4*)(cb + 4);
  ushort4 o0, o1;
  o0.x = f2bf(bf2f(u0.x) * c0.x); o0.y = f2bf(bf2f(u0.y) * c0.y);
  o0.z = f2bf(bf2f(u0.z) * c0.z); o0.w = f2bf(bf2f(u0.w) * c0.w);
  o1.x = f2bf(bf2f(u1.x) * c1.x); o1.y = f2bf(bf2f(u1.y) * c1.y);
  o1.z = f2bf(bf2f(u1.z) * c1.z); o1.w = f2bf(bf2f(u1.w) * c1.w);
  *(ushort4*)(vs + k8) = o0;
  *(ushort4*)(vs + k8 + 4) = o1;
}

// combine partials -> M, 1/Z per (b,col). grid: (cols/256, B)
__global__ __launch_bounds__(256) void colsm_combine(
    const float* __restrict__ red_max, const float* __restrict__ red_sum,
    float* __restrict__ Mv, float* __restrict__ Zinv, int cols, int nch)
{
  const int b = blockIdx.y;
  const int c = blockIdx.x * 256 + threadIdx.x;
  float M = -1e30f, Z = 0.f;
  for (int ch = 0; ch < nch; ++ch) {
    size_t o = ((size_t)b * nch + ch) * cols + c;
    float m = red_max[o], s = red_sum[o];
    float nm = fmaxf(M, m);
    Z = Z * __expf(M - nm) + s * __expf(m - nm);
    M = nm;
  }
  Mv[(size_t)b * cols + c] = M;
  Zinv[(size_t)b * cols + c] = 1.f / Z;
}

// final: out1 = softmax(attn over rows), out0 = attn + residual. attn is bf16.
__global__ __launch_bounds__(256) void final_emit(
    const ushort* __restrict__ attnB, const float* __restrict__ q,
    float* __restrict__ out0, float* __restrict__ out1,
    const float* __restrict__ Mv, const float* __restrict__ Zinv,
    int rows, int cols, int rpc)
{
  const int b = blockIdx.y;
  const int ch = blockIdx.z;
  const size_t base = (size_t)b * rows * cols;
  const int c4 = (blockIdx.x * 256 + threadIdx.x) * 4;
  const int r0 = ch * rpc;
  float M[4], Zi[4];
#pragma unroll
  for (int i = 0; i < 4; ++i) {
    M[i] = Mv[(size_t)b * cols + c4 + i];
    Zi[i] = Zinv[(size_t)b * cols + c4 + i];
  }
  for (int r = r0; r < r0 + rpc; ++r) {
    size_t o = base + (size_t)r * cols + c4;
    ushort4 u = *(const ushort4*)(attnB + o);
    float4 qv = *(const float4*)(q + o);
    float a0 = bf2f(u.x), a1 = bf2f(u.y), a2 = bf2f(u.z), a3 = bf2f(u.w);
    float4 wv, s;
    wv.x = __expf(a0 - M[0]) * Zi[0];
    wv.y = __expf(a1 - M[1]) * Zi[1];
    wv.z = __expf(a2 - M[2]) * Zi[2];
    wv.w = __expf(a3 - M[3]) * Zi[3];
    s.x = a0 + qv.x; s.y = a1 + qv.y; s.z = a2 + qv.z; s.w = a3 + qv.w;
    *(float4*)(out1 + o) = wv;
    *(float4*)(out0 + o) = s;
  }
}

extern "C" void kernel_launch(void* const* d_in, const int* in_sizes, int n_in,
                              void* d_out, int out_size, void* d_ws, size_t ws_size,
                              hipStream_t stream) {
  const float* q  = (const float*)d_in[0];
  const float* k  = (const float*)d_in[1];
  const float* v  = (const float*)d_in[2];
  const float* Wq = (const float*)d_in[3];
  const float* bq = (const float*)d_in[4];
  const float* Wk = (const float*)d_in[5];
  const float* bk = (const float*)d_in[6];
  const float* Wv = (const float*)d_in[7];
  const float* bv = (const float*)d_in[8];
  float* out = (float*)d_out;

  const int B = 8, S = 2048, D = 1024;
  const long BS = (long)B * S;
  const long nQKV = BS * D;
  const long nW = (long)D * D;

  // d_out staging: qb/kb/vb bf16 [0,96M) (dead after vpT GEMM);
  // red_s_sum @96M (512KB), c_s @98M (64KB). final_emit overwrites d_out last.
  ushort* qb = (ushort*)d_out;
  ushort* kb = qb + nQKV;
  ushort* vb = kb + nQKV;
  float* red_s_sum = (float*)((char*)d_out + (96ull << 20));
  float* c_s       = (float*)((char*)d_out + (98ull << 20));

  // workspace map:
  //  [0,32M)  qp  -> (dead after scores)  vs
  //  [32,64M) kp  -> (dead after scores)  attnB
  //  [64,96M) vpT -> (dead after scale_v) red_f_max@64M, red_f_sum@65M, Mf@66M, Zf@67M
  //  [96,160M) Wqb/Wkb/Wvb (early) -> expS bf16 [b][q][k]
  char* ws = (char*)d_ws;
  ushort* qp     = (ushort*)ws;
  ushort* kp     = (ushort*)(ws + (32ull << 20));
  ushort* vpT    = (ushort*)(ws + (64ull << 20));
  ushort* Wqb    = (ushort*)(ws + (96ull << 20));
  ushort* Wkb    = Wqb + nW;
  ushort* Wvb    = Wkb + nW;
  ushort* expS   = (ushort*)(ws + (96ull << 20));
  ushort* vs     = (ushort*)ws;
  ushort* attnB  = (ushort*)(ws + (32ull << 20));
  float* red_f_max = (float*)(ws + (64ull << 20));
  float* red_f_sum = (float*)(ws + (65ull << 20));
  float* Mf        = (float*)(ws + (66ull << 20));
  float* Zf        = (float*)(ws + (67ull << 20));

  const int SH = 131072;
  (void)hipFuncSetAttribute(reinterpret_cast<const void*>(&gemm256<1,0,0,0>),
                            hipFuncAttributeMaxDynamicSharedMemorySize, SH);
  (void)hipFuncSetAttribute(reinterpret_cast<const void*>(&gemm256<2,0,0,0>),
                            hipFuncAttributeMaxDynamicSharedMemorySize, SH);
  (void)hipFuncSetAttribute(reinterpret_cast<const void*>(&gemm256<0,1,2,1>),
                            hipFuncAttributeMaxDynamicSharedMemorySize, SH);
  (void)hipFuncSetAttribute(reinterpret_cast<const void*>(&gemm256<0,0,1,0>),
                            hipFuncAttributeMaxDynamicSharedMemorySize, SH);

  auto cvt = [&](const float* src, ushort* dst, long n) {
    int n4 = (int)(n / 4);
    cvt_f32_bf16<<<dim3((n4 + 255) / 256), 256, 0, stream>>>((const float4*)src, (ushort4*)dst, n4);
  };
  cvt(Wq, Wqb, nW);
  cvt(Wk, Wkb, nW);
  cvt(Wv, Wvb, nW);
  cvt(q, qb, nQKV);
  cvt(k, kb, nQKV);
  cvt(v, vb, nQKV);

  // qp[m][e] = q[m][:]·Wq[e][:] + bq[e]   (gm=64, gn=4)
  gemm256<1,0,0,0><<<dim3(64 * 4), 512, SH, stream>>>(
      qb, Wqb, qp, bq, nullptr, nullptr, D, D, 0, 0, 0, 1.f, 64, 4);
  gemm256<1,0,0,0><<<dim3(64 * 4), 512, SH, stream>>>(
      kb, Wkb, kp, bk, nullptr, nullptr, D, D, 0, 0, 0, 1.f, 64, 4);
  // vpT[b][e][s] = Wv[e][:]·v[b][s][:] + bv[e]   (gm=4, gn=8, batch 8)
  gemm256<2,0,0,0><<<dim3(4 * 8 * B), 512, SH, stream>>>(
      Wvb, vb, vpT, bv, nullptr, nullptr, S, D, 0, (long)S * D, (long)D * S, 1.f, 4, 8);
  // expS = exp(qp·kp^T / 1024) + fused column-sum partials   (gm=8, gn=8, batch 8)
  gemm256<0,1,2,1><<<dim3(8 * 8 * B), 512, SH, stream>>>(
      qp, kp, expS, nullptr, nullptr, red_s_sum,
      S, D, (long)S * D, (long)S * D, (long)S * S, 1.f / 1024.f, 8, 8);

  // c[b,k] = 1/colsum;  vs = vpT * c
  combine_c<<<dim3(S / 256, B), 256, 0, stream>>>(red_s_sum, c_s, S, 8);
  scale_v<<<dim3((int)(nQKV / (256 * 8))), 256, 0, stream>>>(vpT, c_s, vs, S, D * S);

  // attn = expS·vs^T (bf16) + fused final-softmax pass1   (gm=8, gn=4, batch 8)
  gemm256<0,0,1,0><<<dim3(8 * 4 * B), 512, SH, stream>>>(
      expS, vs, attnB, nullptr, red_f_max, red_f_sum,
      D, S, (long)S * S, (long)D * S, (long)S * D, 1.f, 8, 4);

  colsm_combine<<<dim3(D / 256, B), 256, 0, stream>>>(red_f_max, red_f_sum, Mf, Zf, D, 8);
  final_emit<<<dim3(1, B, 128), 256, 0, stream>>>(attnB, q, out, out + nQKV, Mf, Zf, S, D, 16);

  (void)in_sizes; (void)n_in; (void)out_size; (void)ws_size;
}